// Round 25
// baseline (87.694 us; speedup 1.0000x reference)
//
#include <hip/hip_runtime.h>
#include <hip/hip_bf16.h>

// x: (B=4, T=5, C=3, H=128, W=128) fp32 ; R=2 ; D = 60 ; N = 4096
#define BB 4
#define TC 15
#define DD 60
#define NN 4096
#define HH 128
#define DP 64
#define KT 64
#define NWAVE 4
#define QT 64
#define NTILES 64
#define NSPLIT 4
#define L2E 1.4426950408889634f

typedef short s8v __attribute__((ext_vector_type(8)));   // 8 x bf16
typedef ushort u4v __attribute__((ext_vector_type(4)));
typedef float f4v __attribute__((ext_vector_type(4)));
typedef float f2v __attribute__((ext_vector_type(2)));

static __device__ __forceinline__ ushort f2bf_bits(float f) {
    __hip_bfloat16 h = __float2bfloat16(f);
    return *reinterpret_cast<ushort*>(&h);
}
// truncating f32->bf16 (1 op). P-only: bias cancels between numerator and l.
static __device__ __forceinline__ ushort f2bf_trunc(float f) {
    return (ushort)(__float_as_uint(f) >> 16);
}
static __device__ __forceinline__ float bf2f(ushort w) { return __uint_as_float((uint)w << 16); }
static __device__ __forceinline__ float bf2f_lo(uint u) { return __uint_as_float(u << 16); }
static __device__ __forceinline__ float bf2f_hi(uint u) { return __uint_as_float(u & 0xFFFF0000u); }

// ---------- K0 (tiny, launched FIRST): zero mxbits + M = w_w.g_w ; c = w_w.g_b + w_b ----------
// Algebra: out = w_w.Y + w_b with Y = (Z/l).g_w^T + g_b^T  ==>  out = (Z/l).M^T + c.
__global__ __launch_bounds__(256) void k_mw(const float* __restrict__ g_w,
                                            const float* __restrict__ g_b,
                                            const float* __restrict__ w_w,
                                            const float* __restrict__ w_b,
                                            float* __restrict__ Mc,     // [3600 M][60 c]
                                            uint* __restrict__ mxbits) {
    int idx = blockIdx.x * 256 + threadIdx.x;
    if (idx < BB) mxbits[idx] = 0;                     // same-stream: done before k_prep
    if (idx < DD * DD) {
        int p = idx / DD, d = idx % DD;
        float acc = 0.f;
        #pragma unroll
        for (int o = 0; o < DD; ++o)
            acc = fmaf(w_w[p * DD + o], g_w[o * DD + d], acc);
        Mc[idx] = acc;
    } else if (idx < DD * DD + DD) {
        int p = idx - DD * DD;
        float acc = w_b[p];
        #pragma unroll
        for (int o = 0; o < DD; ++o)
            acc = fmaf(w_w[p * DD + o], g_b[o], acc);
        Mc[idx] = acc;
    }
}

// ---------- K1: x -> xf2 (B,64,N) bf16 [rows 0..59 = xf, 60 = 1.0] + xf_t (B,N,64)
//                 + rnorm + per-batch max norm.  TWO adjacent pixels per thread:
// f4v x-loads (16B/lane) and u32 xf2 stores (two pixels' same-d are adjacent). ----------
__global__ __launch_bounds__(256) void k_prep(const float* __restrict__ x,
                                              ushort* __restrict__ xf2,
                                              ushort* __restrict__ xf_t,
                                              float* __restrict__ rnorm,
                                              uint* __restrict__ mxbits) {
    int u = blockIdx.x * 256 + threadIdx.x;            // pixel pair, 0..8191
    int n = u * 2;                                     // even pixel (pair n, n+1)
    int b = n >> 12, nn = n & (NN - 1);
    int oh = nn >> 6, ow = nn & 63;                    // ow even -> f4v 16B-aligned
    const float* xb = x + (size_t)b * TC * HH * HH;
    ushort* x2 = xf2 + (size_t)b * DP * NN + nn;
    ushort row0[DP], row1[DP];
    float ss0 = 0.f, ss1 = 0.f;
    #pragma unroll
    for (int cr = 0; cr < 30; ++cr) {                  // c1 = cr>>1, r1 = cr&1
        int c1 = cr >> 1, r1 = cr & 1;
        f4v v = *(const f4v*)&xb[(c1 * HH + oh * 2 + r1) * HH + ow * 2];
        int d0 = cr * 2;                               // = c1*4 + r1*2
        ushort a0 = f2bf_bits(v[0]), a1 = f2bf_bits(v[1]);   // pixel n:   d0, d0+1
        ushort b0 = f2bf_bits(v[2]), b1 = f2bf_bits(v[3]);   // pixel n+1: d0, d0+1
        row0[d0] = a0; row0[d0 + 1] = a1;
        row1[d0] = b0; row1[d0 + 1] = b1;
        float fa0 = bf2f(a0), fa1 = bf2f(a1), fb0 = bf2f(b0), fb1 = bf2f(b1);
        ss0 = fmaf(fa0, fa0, ss0); ss0 = fmaf(fa1, fa1, ss0);
        ss1 = fmaf(fb0, fb0, ss1); ss1 = fmaf(fb1, fb1, ss1);
        *(uint*)&x2[(size_t)d0 * NN]       = (uint)a0 | ((uint)b0 << 16);
        *(uint*)&x2[(size_t)(d0 + 1) * NN] = (uint)a1 | ((uint)b1 << 16);
    }
    *(uint*)&x2[(size_t)60 * NN] = 0x3F803F80u;        // ones row -> l accumulator
    *(uint*)&x2[(size_t)61 * NN] = 0u;
    *(uint*)&x2[(size_t)62 * NN] = 0u;
    *(uint*)&x2[(size_t)63 * NN] = 0u;
    #pragma unroll
    for (int d = DD; d < DP; ++d) { row0[d] = 0; row1[d] = 0; }
    ushort* dst = xf_t + (size_t)n * DP;
    #pragma unroll
    for (int j = 0; j < 8; ++j) {
        *(s8v*)&dst[j * 8]      = *(const s8v*)&row0[j * 8];
        *(s8v*)&dst[DP + j * 8] = *(const s8v*)&row1[j * 8];
    }
    float nr0 = sqrtf(ss0) * 1.0002f;                  // safety margin: m bounds row max
    float nr1 = sqrtf(ss1) * 1.0002f;
    *(f2v*)&rnorm[n] = (f2v){nr0, nr1};
    float mv = fmaxf(nr0, nr1);
    #pragma unroll
    for (int off = 1; off < 64; off <<= 1) mv = fmaxf(mv, __shfl_xor(mv, off));
    if ((threadIdx.x & 63) == 0) atomicMax(&mxbits[b], __float_as_uint(mv));
}

// ---------- K3: flash attention, split-K=4. Z = P.X^T with xf2 row 60 = 1 -> l.
// LDS single-buffer 24KB, 2 barriers/tile, reg-prefetch, P/PV interleave.
// m_n = rnorm[n]*mxnorm[b] fixed softmax shift (Cauchy-Schwarz upper bound).
// ALL NS write unnormalized Z (+l col); k_cout applies M and divides. UNCHANGED from r24.
template <int NS>
__global__ __launch_bounds__(256, 2) void k_attn(const ushort* __restrict__ xf_t,
                                                 const ushort* __restrict__ x2_bf, // (B,64,N)
                                                 const float* __restrict__ rnorm,
                                                 const uint* __restrict__ mxbits,
                                                 ushort* __restrict__ O_bf) {  // (s,b,64,N) bf16
    __shared__ char K_lds[KT * 128];                   // 8 KB
    __shared__ char G_lds[DP * 128];                   // 8 KB (X^T tile)
    __shared__ char P_lds[NWAVE][16 * 128];            // 8 KB

    int p = blockIdx.x;
    int s, b, q0;
    if (NS == NSPLIT) {
        // XCD-aware: xcd = p&7; each XCD pair-half owns one batch (~1MB = L2-hot)
        int xcd = p & 7, slot = p >> 3;                // slot in [0,128)
        b = xcd >> 1;
        s = (xcd & 1) * 2 + (slot >> 6);               // NS=4: 2 splits per xcd-half
        q0 = (slot & 63) * QT;
    } else {
        s = 0;
        b = p >> 6;
        q0 = (p & 63) * QT;
    }
    int tid = threadIdx.x;
    int lane = tid & 63, wv = tid >> 6;
    int r = lane & 15, g = lane >> 4;

    const ushort* Xt = xf_t + (size_t)b * NN * DP;
    const ushort* Gb = x2_bf + (size_t)b * DP * NN;

    int qrow = q0 + wv * 16 + r;
    s8v qa[2];
    qa[0] = *(const s8v*)&Xt[(size_t)qrow * DP + g * 8];
    qa[1] = *(const s8v*)&Xt[(size_t)qrow * DP + 32 + g * 8];

    // fixed per-row shift, rows 4g+0..3 of this lane
    float mx = __uint_as_float(mxbits[b]);
    float nm[4];
    #pragma unroll
    for (int reg = 0; reg < 4; ++reg)
        nm[reg] = -rnorm[b * NN + q0 + wv * 16 + 4 * g + reg] * mx * L2E;

    f4v of[4];
    #pragma unroll
    for (int i = 0; i < 4; ++i) of[i] = (f4v){0.f, 0.f, 0.f, 0.f};

    // staging: 256 threads x two 16B units per buffer; row = e>>3, j = e&7
    const int e0 = tid, e1 = 256 + tid;
    const int kr0 = e0 >> 3, kj0 = e0 & 7;             // rows 0..31
    const int kr1 = e1 >> 3, kj1 = e1 & 7;             // rows 32..63
    const int kw0 = (kr0 * 128 + kj0 * 16) ^ ((kr0 & 7) << 4);
    const int kw1 = (kr1 * 128 + kj1 * 16) ^ ((kr1 & 7) << 4);
    s8v kp0, kp1, gp0, gp1;

    auto stage_regs = [&](int t) {
        int n0 = t * KT;
        kp0 = *(const s8v*)&Xt[(size_t)(n0 + kr0) * DP + kj0 * 8];
        kp1 = *(const s8v*)&Xt[(size_t)(n0 + kr1) * DP + kj1 * 8];
        gp0 = *(const s8v*)&Gb[(size_t)kr0 * NN + n0 + kj0 * 8];   // branch-free: 64 rows
        gp1 = *(const s8v*)&Gb[(size_t)kr1 * NN + n0 + kj1 * 8];
    };
    auto lds_write = [&]() {
        *(s8v*)(K_lds + kw0) = kp0;
        *(s8v*)(K_lds + kw1) = kp1;
        *(s8v*)(G_lds + kw0) = gp0;
        *(s8v*)(G_lds + kw1) = gp1;
    };

    const int t0 = s * (NTILES / NS);
    const int tend = t0 + NTILES / NS;
    char* Pw = P_lds[wv];

    stage_regs(t0);
    lds_write();
    __syncthreads();

    #pragma unroll 1
    for (int t = t0; t < tend; ++t) {
        bool more = (t + 1 < tend);
        if (more) stage_regs(t + 1);          // global loads in flight during compute

        // ---- S = Q.K^T ----
        f4v sf[4];
        #pragma unroll
        for (int i = 0; i < 4; ++i) sf[i] = (f4v){0.f, 0.f, 0.f, 0.f};
        #pragma unroll
        for (int kt2 = 0; kt2 < 4; ++kt2)
            #pragma unroll
            for (int kb = 0; kb < 2; ++kb) {
                int off = (((kt2 * 16 + r) * 128) + kb * 64 + g * 16) ^ ((r & 7) << 4);
                s8v bf = *(const s8v*)(K_lds + off);
                sf[kt2] = __builtin_amdgcn_mfma_f32_16x16x32_bf16(qa[kb], bf, sf[kt2], 0, 0, 0);
            }

        // ---- P for keys 0..31 (kt2 = 0,1), truncating cvt ----
        #pragma unroll
        for (int kt2 = 0; kt2 < 2; ++kt2)
            #pragma unroll
            for (int reg = 0; reg < 4; ++reg) {
                float pv = __builtin_exp2f(fmaf(sf[kt2][reg], L2E, nm[reg]));
                int row = 4 * g + reg;
                int boff = ((row * 128) + kt2 * 32 + 2 * r) ^ ((row & 7) << 4);
                *(ushort*)(Pw + boff) = f2bf_trunc(pv);
            }
        // ---- Z += P.X^T kb=0 (wave-internal LDS is in-order) ----
        {
            int poff = ((r * 128) + g * 16) ^ ((r & 7) << 4);
            s8v pa = *(const s8v*)(Pw + poff);
            #pragma unroll
            for (int ot = 0; ot < 4; ++ot) {
                int goff = (((ot * 16 + r) * 128) + g * 16) ^ ((r & 7) << 4);
                s8v gf = *(const s8v*)(G_lds + goff);
                of[ot] = __builtin_amdgcn_mfma_f32_16x16x32_bf16(pa, gf, of[ot], 0, 0, 0);
            }
        }
        // ---- P for keys 32..63 (kt2 = 2,3), truncating cvt ----
        #pragma unroll
        for (int kt2 = 2; kt2 < 4; ++kt2)
            #pragma unroll
            for (int reg = 0; reg < 4; ++reg) {
                float pv = __builtin_exp2f(fmaf(sf[kt2][reg], L2E, nm[reg]));
                int row = 4 * g + reg;
                int boff = ((row * 128) + kt2 * 32 + 2 * r) ^ ((row & 7) << 4);
                *(ushort*)(Pw + boff) = f2bf_trunc(pv);
            }
        // ---- Z += P.X^T kb=1 ----
        {
            int poff = ((r * 128) + 64 + g * 16) ^ ((r & 7) << 4);
            s8v pa = *(const s8v*)(Pw + poff);
            #pragma unroll
            for (int ot = 0; ot < 4; ++ot) {
                int goff = (((ot * 16 + r) * 128) + 64 + g * 16) ^ ((r & 7) << 4);
                s8v gf = *(const s8v*)(G_lds + goff);
                of[ot] = __builtin_amdgcn_mfma_f32_16x16x32_bf16(pa, gf, of[ot], 0, 0, 0);
            }
        }

        if (more) {
            __syncthreads();                  // all waves done reading K/X^T
            lds_write();
            __syncthreads();                  // next tile staged
        }
    }

    // epilogue: unnormalized Z (+ l in col 60); k_cout applies M and divides
    int qb = q0 + wv * 16 + 4 * g;
    ushort* Ob = O_bf + ((size_t)(s * BB + b) * DP) * NN;
    #pragma unroll
    for (int ot = 0; ot < 4; ++ot) {
        int o = ot * 16 + r;
        u4v v = {f2bf_bits(of[ot][0]), f2bf_bits(of[ot][1]),
                 f2bf_bits(of[ot][2]), f2bf_bits(of[ot][3])};
        *(u4v*)&Ob[(size_t)o * NN + qb] = v;                 // coalesced 32B per r-group
    }
}

// ---------- K4 (fused combine+out): block per 64 pixels. Phase 1: sum NS splits
// via u32 pair-loads into z_lds[64][61] f32 + linv from l col (o=60). Phase 2:
// out[p] = (M[p].z)*linv + c[p] + x, 1 pixel x 15 outputs per thread (o wave-uniform).
template <int NS>
__global__ __launch_bounds__(256) void k_cout(const ushort* __restrict__ O_bf,
                                              const float* __restrict__ Mc,
                                              const float* __restrict__ x,
                                              float* __restrict__ out) {
    __shared__ float ww[DD * DD];                      // 14.4 KB (= M)
    __shared__ float wb[DD];                           //          (= c)
    __shared__ float zlds[64][61];                     // 15.6 KB
    __shared__ float linv[64];

    int b  = blockIdx.x >> 6;                          // grid = BB*64
    int n0 = (blockIdx.x & 63) * 64;
    int tid = threadIdx.x;
    for (int i = tid; i < DD * DD; i += 256) ww[i] = Mc[i];
    if (tid < DD) wb[tid] = Mc[DD * DD + tid];

    // ---- phase 1: pixel-pair pp = tid&31 (pixels 2pp, 2pp+1), o-group tid>>5 ----
    int pp   = tid & 31;
    int ogrp = tid >> 5;                               // 0..7
    const ushort* Op = O_bf + (size_t)b * DP * NN + n0 + 2 * pp;
    #pragma unroll
    for (int i = 0; i < 8; ++i) {
        int o = ogrp * 8 + i;                          // 0..63
        if (o > DD) continue;                          // o<=60 processed
        float s0 = 0.f, s1 = 0.f;
        #pragma unroll
        for (int ss = 0; ss < NS; ++ss) {
            uint v = *(const uint*)&Op[(size_t)ss * BB * DP * NN + (size_t)o * NN];
            s0 += bf2f_lo(v);
            s1 += bf2f_hi(v);
        }
        if (o < DD) { zlds[2 * pp][o] = s0; zlds[2 * pp + 1][o] = s1; }
        else        { linv[2 * pp] = 1.0f / s0; linv[2 * pp + 1] = 1.0f / s1; }
    }
    __syncthreads();

    // ---- phase 2: pixel = tid&63, outputs o = (tid>>6)*15 + k (wave-uniform o) ----
    int pix = tid & 63;
    int og  = tid >> 6;                                // 0..3
    float li = linv[pix];
    int n = n0 + pix;
    int oh = n >> 6, ow = n & 63;
    #pragma unroll
    for (int k = 0; k < 15; ++k) {
        int o = og * 15 + k;                           // 0..59, each exactly once
        float acc = 0.f;
        #pragma unroll
        for (int d = 0; d < DD; ++d)
            acc = fmaf(ww[o * DD + d], zlds[pix][d], acc);
        int c1 = o >> 2, r1 = (o >> 1) & 1, r2 = o & 1;
        size_t xi = ((size_t)(b * TC + c1) * HH + 2 * oh + r1) * HH + 2 * ow + r2;
        out[xi] = fmaf(acc, li, wb[o]) + x[xi];
    }
}

extern "C" void kernel_launch(void* const* d_in, const int* in_sizes, int n_in,
                              void* d_out, int out_size, void* d_ws, size_t ws_size,
                              hipStream_t stream) {
    const float* x   = (const float*)d_in[0];
    const float* g_w = (const float*)d_in[1];
    const float* g_b = (const float*)d_in[2];
    const float* w_w = (const float*)d_in[3];
    const float* w_b = (const float*)d_in[4];
    float* out = (float*)d_out;

    char* ws = (char*)d_ws;
    ushort* xf2    = (ushort*)ws;                      // 2,097,152 B (B,64,N)
    ushort* xf_t   = (ushort*)(ws + 2097152);          // 2,097,152 B (B,N,64)
    float*  rnorm  = (float*)(ws + 4194304);           // 65,536 B
    uint*   mxbits = (uint*)(ws + 4259840);            // 256 B
    float*  Mc     = (float*)(ws + 4260096);           // 16,384 B  (3600 M + 60 c)
    ushort* O_bf   = (ushort*)(ws + 4276480);          // 8,388,608 B (NS=4) -> end 12,665,088
    const size_t SPLIT_NEED = 12665088;

    k_mw<<<16, 256, 0, stream>>>(g_w, g_b, w_w, w_b, Mc, mxbits);  // also zeroes mxbits
    k_prep<<<BB * NN / 512, 256, 0, stream>>>(x, xf2, xf_t, rnorm, mxbits);

    if (ws_size >= SPLIT_NEED) {
        k_attn<NSPLIT><<<NSPLIT * BB * (NN / QT), 256, 0, stream>>>(
            xf_t, xf2, rnorm, mxbits, O_bf);
        k_cout<NSPLIT><<<BB * 64, 256, 0, stream>>>(O_bf, Mc, x, out);
    } else {
        k_attn<1><<<BB * (NN / QT), 256, 0, stream>>>(
            xf_t, xf2, rnorm, mxbits, O_bf);
        k_cout<1><<<BB * 64, 256, 0, stream>>>(O_bf, Mc, x, out);
    }
}

// Round 26
// 75.166 us; speedup vs baseline: 1.1667x; 1.1667x over previous
//
#include <hip/hip_runtime.h>
#include <hip/hip_bf16.h>

// x: (B=4, T=5, C=3, H=128, W=128) fp32 ; R=2 ; D = 60 ; N = 4096
#define BB 4
#define TC 15
#define DD 60
#define NN 4096
#define HH 128
#define DP 64
#define KT 64
#define NWAVE 4
#define QT 64
#define NTILES 64
#define NSPLIT 4
#define L2E 1.4426950408889634f

typedef short s8v __attribute__((ext_vector_type(8)));   // 8 x bf16
typedef ushort u4v __attribute__((ext_vector_type(4)));
typedef float f4v __attribute__((ext_vector_type(4)));
typedef float f2v __attribute__((ext_vector_type(2)));

static __device__ __forceinline__ ushort f2bf_bits(float f) {
    __hip_bfloat16 h = __float2bfloat16(f);
    return *reinterpret_cast<ushort*>(&h);
}
// truncating f32->bf16 (1 op). P-only: bias cancels between numerator and l.
static __device__ __forceinline__ ushort f2bf_trunc(float f) {
    return (ushort)(__float_as_uint(f) >> 16);
}
static __device__ __forceinline__ float bf2f(ushort w) { return __uint_as_float((uint)w << 16); }
static __device__ __forceinline__ float bf2f_lo(uint u) { return __uint_as_float(u << 16); }
static __device__ __forceinline__ float bf2f_hi(uint u) { return __uint_as_float(u & 0xFFFF0000u); }

// ---------- K0 (tiny, launched FIRST): zero mxbits + M = w_w.g_w ; c = w_w.g_b + w_b ----------
// Algebra: out = w_w.Y + w_b with Y = (Z/l).g_w^T + g_b^T  ==>  out = (Z/l).M^T + c.
__global__ __launch_bounds__(256) void k_mw(const float* __restrict__ g_w,
                                            const float* __restrict__ g_b,
                                            const float* __restrict__ w_w,
                                            const float* __restrict__ w_b,
                                            float* __restrict__ Mc,     // [3600 M][60 c]
                                            uint* __restrict__ mxbits) {
    int idx = blockIdx.x * 256 + threadIdx.x;
    if (idx < BB) mxbits[idx] = 0;                     // same-stream: done before k_prep
    if (idx < DD * DD) {
        int p = idx / DD, d = idx % DD;
        float acc = 0.f;
        #pragma unroll
        for (int o = 0; o < DD; ++o)
            acc = fmaf(w_w[p * DD + o], g_w[o * DD + d], acc);
        Mc[idx] = acc;
    } else if (idx < DD * DD + DD) {
        int p = idx - DD * DD;
        float acc = w_b[p];
        #pragma unroll
        for (int o = 0; o < DD; ++o)
            acc = fmaf(w_w[p * DD + o], g_b[o], acc);
        Mc[idx] = acc;
    }
}

// ---------- K1: x -> xf2 (B,64,N) bf16 [rows 0..59 = xf, 60 = 1.0] + xf_t (B,N,64)
//                 + rnorm + per-batch max norm.  TWO adjacent pixels per thread:
// f4v x-loads (16B/lane) and u32 xf2 stores (two pixels' same-d are adjacent). ----------
__global__ __launch_bounds__(256) void k_prep(const float* __restrict__ x,
                                              ushort* __restrict__ xf2,
                                              ushort* __restrict__ xf_t,
                                              float* __restrict__ rnorm,
                                              uint* __restrict__ mxbits) {
    int u = blockIdx.x * 256 + threadIdx.x;            // pixel pair, 0..8191
    int n = u * 2;                                     // even pixel (pair n, n+1)
    int b = n >> 12, nn = n & (NN - 1);
    int oh = nn >> 6, ow = nn & 63;                    // ow even -> f4v 16B-aligned
    const float* xb = x + (size_t)b * TC * HH * HH;
    ushort* x2 = xf2 + (size_t)b * DP * NN + nn;
    ushort row0[DP], row1[DP];
    float ss0 = 0.f, ss1 = 0.f;
    #pragma unroll
    for (int cr = 0; cr < 30; ++cr) {                  // c1 = cr>>1, r1 = cr&1
        int c1 = cr >> 1, r1 = cr & 1;
        f4v v = *(const f4v*)&xb[(c1 * HH + oh * 2 + r1) * HH + ow * 2];
        int d0 = cr * 2;                               // = c1*4 + r1*2
        ushort a0 = f2bf_bits(v[0]), a1 = f2bf_bits(v[1]);   // pixel n:   d0, d0+1
        ushort b0 = f2bf_bits(v[2]), b1 = f2bf_bits(v[3]);   // pixel n+1: d0, d0+1
        row0[d0] = a0; row0[d0 + 1] = a1;
        row1[d0] = b0; row1[d0 + 1] = b1;
        float fa0 = bf2f(a0), fa1 = bf2f(a1), fb0 = bf2f(b0), fb1 = bf2f(b1);
        ss0 = fmaf(fa0, fa0, ss0); ss0 = fmaf(fa1, fa1, ss0);
        ss1 = fmaf(fb0, fb0, ss1); ss1 = fmaf(fb1, fb1, ss1);
        *(uint*)&x2[(size_t)d0 * NN]       = (uint)a0 | ((uint)b0 << 16);
        *(uint*)&x2[(size_t)(d0 + 1) * NN] = (uint)a1 | ((uint)b1 << 16);
    }
    *(uint*)&x2[(size_t)60 * NN] = 0x3F803F80u;        // ones row -> l accumulator
    *(uint*)&x2[(size_t)61 * NN] = 0u;
    *(uint*)&x2[(size_t)62 * NN] = 0u;
    *(uint*)&x2[(size_t)63 * NN] = 0u;
    #pragma unroll
    for (int d = DD; d < DP; ++d) { row0[d] = 0; row1[d] = 0; }
    ushort* dst = xf_t + (size_t)n * DP;
    #pragma unroll
    for (int j = 0; j < 8; ++j) {
        *(s8v*)&dst[j * 8]      = *(const s8v*)&row0[j * 8];
        *(s8v*)&dst[DP + j * 8] = *(const s8v*)&row1[j * 8];
    }
    float nr0 = sqrtf(ss0) * 1.0002f;                  // safety margin: m bounds row max
    float nr1 = sqrtf(ss1) * 1.0002f;
    *(f2v*)&rnorm[n] = (f2v){nr0, nr1};
    float mv = fmaxf(nr0, nr1);
    #pragma unroll
    for (int off = 1; off < 64; off <<= 1) mv = fmaxf(mv, __shfl_xor(mv, off));
    if ((threadIdx.x & 63) == 0) atomicMax(&mxbits[b], __float_as_uint(mv));
}

// ---------- K3: flash attention, split-K=4. Z = P.X^T with xf2 row 60 = 1 -> l.
// LDS single-buffer 24KB, 2 barriers/tile, reg-prefetch, P/PV interleave.
// m_n = rnorm[n]*mxnorm[b] fixed softmax shift (Cauchy-Schwarz upper bound).
// ALL NS write unnormalized Z (+l col); k_cout applies M and divides. UNCHANGED.
template <int NS>
__global__ __launch_bounds__(256, 2) void k_attn(const ushort* __restrict__ xf_t,
                                                 const ushort* __restrict__ x2_bf, // (B,64,N)
                                                 const float* __restrict__ rnorm,
                                                 const uint* __restrict__ mxbits,
                                                 ushort* __restrict__ O_bf) {  // (s,b,64,N) bf16
    __shared__ char K_lds[KT * 128];                   // 8 KB
    __shared__ char G_lds[DP * 128];                   // 8 KB (X^T tile)
    __shared__ char P_lds[NWAVE][16 * 128];            // 8 KB

    int p = blockIdx.x;
    int s, b, q0;
    if (NS == NSPLIT) {
        // XCD-aware: xcd = p&7; each XCD pair-half owns one batch (~1MB = L2-hot)
        int xcd = p & 7, slot = p >> 3;                // slot in [0,128)
        b = xcd >> 1;
        s = (xcd & 1) * 2 + (slot >> 6);               // NS=4: 2 splits per xcd-half
        q0 = (slot & 63) * QT;
    } else {
        s = 0;
        b = p >> 6;
        q0 = (p & 63) * QT;
    }
    int tid = threadIdx.x;
    int lane = tid & 63, wv = tid >> 6;
    int r = lane & 15, g = lane >> 4;

    const ushort* Xt = xf_t + (size_t)b * NN * DP;
    const ushort* Gb = x2_bf + (size_t)b * DP * NN;

    int qrow = q0 + wv * 16 + r;
    s8v qa[2];
    qa[0] = *(const s8v*)&Xt[(size_t)qrow * DP + g * 8];
    qa[1] = *(const s8v*)&Xt[(size_t)qrow * DP + 32 + g * 8];

    // fixed per-row shift, rows 4g+0..3 of this lane
    float mx = __uint_as_float(mxbits[b]);
    float nm[4];
    #pragma unroll
    for (int reg = 0; reg < 4; ++reg)
        nm[reg] = -rnorm[b * NN + q0 + wv * 16 + 4 * g + reg] * mx * L2E;

    f4v of[4];
    #pragma unroll
    for (int i = 0; i < 4; ++i) of[i] = (f4v){0.f, 0.f, 0.f, 0.f};

    // staging: 256 threads x two 16B units per buffer; row = e>>3, j = e&7
    const int e0 = tid, e1 = 256 + tid;
    const int kr0 = e0 >> 3, kj0 = e0 & 7;             // rows 0..31
    const int kr1 = e1 >> 3, kj1 = e1 & 7;             // rows 32..63
    const int kw0 = (kr0 * 128 + kj0 * 16) ^ ((kr0 & 7) << 4);
    const int kw1 = (kr1 * 128 + kj1 * 16) ^ ((kr1 & 7) << 4);
    s8v kp0, kp1, gp0, gp1;

    auto stage_regs = [&](int t) {
        int n0 = t * KT;
        kp0 = *(const s8v*)&Xt[(size_t)(n0 + kr0) * DP + kj0 * 8];
        kp1 = *(const s8v*)&Xt[(size_t)(n0 + kr1) * DP + kj1 * 8];
        gp0 = *(const s8v*)&Gb[(size_t)kr0 * NN + n0 + kj0 * 8];   // branch-free: 64 rows
        gp1 = *(const s8v*)&Gb[(size_t)kr1 * NN + n0 + kj1 * 8];
    };
    auto lds_write = [&]() {
        *(s8v*)(K_lds + kw0) = kp0;
        *(s8v*)(K_lds + kw1) = kp1;
        *(s8v*)(G_lds + kw0) = gp0;
        *(s8v*)(G_lds + kw1) = gp1;
    };

    const int t0 = s * (NTILES / NS);
    const int tend = t0 + NTILES / NS;
    char* Pw = P_lds[wv];

    stage_regs(t0);
    lds_write();
    __syncthreads();

    #pragma unroll 1
    for (int t = t0; t < tend; ++t) {
        bool more = (t + 1 < tend);
        if (more) stage_regs(t + 1);          // global loads in flight during compute

        // ---- S = Q.K^T ----
        f4v sf[4];
        #pragma unroll
        for (int i = 0; i < 4; ++i) sf[i] = (f4v){0.f, 0.f, 0.f, 0.f};
        #pragma unroll
        for (int kt2 = 0; kt2 < 4; ++kt2)
            #pragma unroll
            for (int kb = 0; kb < 2; ++kb) {
                int off = (((kt2 * 16 + r) * 128) + kb * 64 + g * 16) ^ ((r & 7) << 4);
                s8v bf = *(const s8v*)(K_lds + off);
                sf[kt2] = __builtin_amdgcn_mfma_f32_16x16x32_bf16(qa[kb], bf, sf[kt2], 0, 0, 0);
            }

        // ---- P for keys 0..31 (kt2 = 0,1), truncating cvt ----
        #pragma unroll
        for (int kt2 = 0; kt2 < 2; ++kt2)
            #pragma unroll
            for (int reg = 0; reg < 4; ++reg) {
                float pv = __builtin_exp2f(fmaf(sf[kt2][reg], L2E, nm[reg]));
                int row = 4 * g + reg;
                int boff = ((row * 128) + kt2 * 32 + 2 * r) ^ ((row & 7) << 4);
                *(ushort*)(Pw + boff) = f2bf_trunc(pv);
            }
        // ---- Z += P.X^T kb=0 (wave-internal LDS is in-order) ----
        {
            int poff = ((r * 128) + g * 16) ^ ((r & 7) << 4);
            s8v pa = *(const s8v*)(Pw + poff);
            #pragma unroll
            for (int ot = 0; ot < 4; ++ot) {
                int goff = (((ot * 16 + r) * 128) + g * 16) ^ ((r & 7) << 4);
                s8v gf = *(const s8v*)(G_lds + goff);
                of[ot] = __builtin_amdgcn_mfma_f32_16x16x32_bf16(pa, gf, of[ot], 0, 0, 0);
            }
        }
        // ---- P for keys 32..63 (kt2 = 2,3), truncating cvt ----
        #pragma unroll
        for (int kt2 = 2; kt2 < 4; ++kt2)
            #pragma unroll
            for (int reg = 0; reg < 4; ++reg) {
                float pv = __builtin_exp2f(fmaf(sf[kt2][reg], L2E, nm[reg]));
                int row = 4 * g + reg;
                int boff = ((row * 128) + kt2 * 32 + 2 * r) ^ ((row & 7) << 4);
                *(ushort*)(Pw + boff) = f2bf_trunc(pv);
            }
        // ---- Z += P.X^T kb=1 ----
        {
            int poff = ((r * 128) + 64 + g * 16) ^ ((r & 7) << 4);
            s8v pa = *(const s8v*)(Pw + poff);
            #pragma unroll
            for (int ot = 0; ot < 4; ++ot) {
                int goff = (((ot * 16 + r) * 128) + 64 + g * 16) ^ ((r & 7) << 4);
                s8v gf = *(const s8v*)(G_lds + goff);
                of[ot] = __builtin_amdgcn_mfma_f32_16x16x32_bf16(pa, gf, of[ot], 0, 0, 0);
            }
        }

        if (more) {
            __syncthreads();                  // all waves done reading K/X^T
            lds_write();
            __syncthreads();                  // next tile staged
        }
    }

    // epilogue: unnormalized Z (+ l in col 60); k_cout applies M and divides
    int qb = q0 + wv * 16 + 4 * g;
    ushort* Ob = O_bf + ((size_t)(s * BB + b) * DP) * NN;
    #pragma unroll
    for (int ot = 0; ot < 4; ++ot) {
        int o = ot * 16 + r;
        u4v v = {f2bf_bits(of[ot][0]), f2bf_bits(of[ot][1]),
                 f2bf_bits(of[ot][2]), f2bf_bits(of[ot][3])};
        *(u4v*)&Ob[(size_t)o * NN + qb] = v;                 // coalesced 32B per r-group
    }
}

// ---------- K4 (fused combine+out): EXACT round-24 proven version (block per 32
// pixels, grid BB*128, 8 outputs/thread). Phase 1: sum NS splits into z_lds[32][61]
// f32 + linv from l col (o=60). Phase 2: out[p] = (M[p].z)*linv + c[p] + x.
template <int NS>
__global__ __launch_bounds__(256) void k_cout(const ushort* __restrict__ O_bf,
                                              const float* __restrict__ Mc,
                                              const float* __restrict__ x,
                                              float* __restrict__ out) {
    __shared__ float ww[DD * DD];                      // 14.4 KB (= M)
    __shared__ float wb[DD];                           //          (= c)
    __shared__ float zlds[32][61];                     // 7.8 KB
    __shared__ float linv[32];

    int b  = blockIdx.x >> 7;                          // grid = BB*128
    int n0 = (blockIdx.x & 127) * 32;
    int tid = threadIdx.x;
    for (int i = tid; i < DD * DD; i += 256) ww[i] = Mc[i];
    if (tid < DD) wb[tid] = Mc[DD * DD + tid];

    int pix  = tid & 31;
    int ogrp = tid >> 5;                               // 0..7
    int n = n0 + pix;

    // ---- phase 1: z[pix][d] = sum_s Z_s[d][n] ; linv[pix] = 1/sum_s Z_s[60][n] ----
    const ushort* Op = O_bf + (size_t)b * DP * NN + n;
    #pragma unroll
    for (int i = 0; i < 8; ++i) {
        int o = ogrp * 8 + i;                          // 0..63
        if (o > DD) continue;                          // o<=60 processed
        float sum = 0.f;
        #pragma unroll
        for (int ss = 0; ss < NS; ++ss)
            sum += bf2f(Op[(size_t)ss * BB * DP * NN + (size_t)o * NN]);
        if (o < DD) zlds[pix][o] = sum;
        else        linv[pix] = 1.0f / sum;            // o == 60
    }
    __syncthreads();

    // ---- phase 2: 8 outputs per thread (p = 8k+ogrp), M from LDS, z from LDS ----
    float li = linv[pix];
    int oh = n >> 6, ow = n & 63;
    #pragma unroll
    for (int k = 0; k < 8; ++k) {
        int o = k * 8 + ogrp;
        if (o < DD) {
            float acc = 0.f;
            #pragma unroll
            for (int d = 0; d < DD; ++d)
                acc = fmaf(ww[o * DD + d], zlds[pix][d], acc);
            int c1 = o >> 2, r1 = (o >> 1) & 1, r2 = o & 1;
            size_t xi = ((size_t)(b * TC + c1) * HH + 2 * oh + r1) * HH + 2 * ow + r2;
            out[xi] = fmaf(acc, li, wb[o]) + x[xi];
        }
    }
}

extern "C" void kernel_launch(void* const* d_in, const int* in_sizes, int n_in,
                              void* d_out, int out_size, void* d_ws, size_t ws_size,
                              hipStream_t stream) {
    const float* x   = (const float*)d_in[0];
    const float* g_w = (const float*)d_in[1];
    const float* g_b = (const float*)d_in[2];
    const float* w_w = (const float*)d_in[3];
    const float* w_b = (const float*)d_in[4];
    float* out = (float*)d_out;

    char* ws = (char*)d_ws;
    ushort* xf2    = (ushort*)ws;                      // 2,097,152 B (B,64,N)
    ushort* xf_t   = (ushort*)(ws + 2097152);          // 2,097,152 B (B,N,64)
    float*  rnorm  = (float*)(ws + 4194304);           // 65,536 B
    uint*   mxbits = (uint*)(ws + 4259840);            // 256 B
    float*  Mc     = (float*)(ws + 4260096);           // 16,384 B  (3600 M + 60 c)
    ushort* O_bf   = (ushort*)(ws + 4276480);          // 8,388,608 B (NS=4) -> end 12,665,088
    const size_t SPLIT_NEED = 12665088;

    k_mw<<<16, 256, 0, stream>>>(g_w, g_b, w_w, w_b, Mc, mxbits);  // also zeroes mxbits
    k_prep<<<BB * NN / 512, 256, 0, stream>>>(x, xf2, xf_t, rnorm, mxbits);

    if (ws_size >= SPLIT_NEED) {
        k_attn<NSPLIT><<<NSPLIT * BB * (NN / QT), 256, 0, stream>>>(
            xf_t, xf2, rnorm, mxbits, O_bf);
        k_cout<NSPLIT><<<BB * 128, 256, 0, stream>>>(O_bf, Mc, x, out);
    } else {
        k_attn<1><<<BB * (NN / QT), 256, 0, stream>>>(
            xf_t, xf2, rnorm, mxbits, O_bf);
        k_cout<1><<<BB * 128, 256, 0, stream>>>(O_bf, Mc, x, out);
    }
}

// Round 27
// 70.607 us; speedup vs baseline: 1.2420x; 1.0646x over previous
//
#include <hip/hip_runtime.h>
#include <hip/hip_bf16.h>

// x: (B=4, T=5, C=3, H=128, W=128) fp32 ; R=2 ; D = 60 ; N = 4096
#define BB 4
#define TC 15
#define DD 60
#define NN 4096
#define HH 128
#define DP 64
#define KT 64
#define NWAVE 4
#define QT 64
#define NTILES 64
#define NSPLIT 4
#define L2E 1.4426950408889634f

typedef short s8v __attribute__((ext_vector_type(8)));   // 8 x bf16
typedef ushort u4v __attribute__((ext_vector_type(4)));
typedef float f4v __attribute__((ext_vector_type(4)));
typedef float f2v __attribute__((ext_vector_type(2)));

static __device__ __forceinline__ ushort f2bf_bits(float f) {
    __hip_bfloat16 h = __float2bfloat16(f);
    return *reinterpret_cast<ushort*>(&h);
}
// truncating f32->bf16 (1 op). P-only: bias cancels between numerator and l.
static __device__ __forceinline__ ushort f2bf_trunc(float f) {
    return (ushort)(__float_as_uint(f) >> 16);
}
static __device__ __forceinline__ float bf2f(ushort w) { return __uint_as_float((uint)w << 16); }

// ---------- K0 (tiny, launched FIRST): zero mxbits + M = w_w.g_w ; c = w_w.g_b + w_b ----------
// Algebra: out = w_w.Y + w_b with Y = (Z/l).g_w^T + g_b^T  ==>  out = (Z/l).M^T + c.
__global__ __launch_bounds__(256) void k_mw(const float* __restrict__ g_w,
                                            const float* __restrict__ g_b,
                                            const float* __restrict__ w_w,
                                            const float* __restrict__ w_b,
                                            float* __restrict__ Mc,     // [3600 M][60 c]
                                            uint* __restrict__ mxbits) {
    int idx = blockIdx.x * 256 + threadIdx.x;
    if (idx < BB) mxbits[idx] = 0;                     // same-stream: done before k_prep
    if (idx < DD * DD) {
        int p = idx / DD, d = idx % DD;
        float acc = 0.f;
        #pragma unroll
        for (int o = 0; o < DD; ++o)
            acc = fmaf(w_w[p * DD + o], g_w[o * DD + d], acc);
        Mc[idx] = acc;
    } else if (idx < DD * DD + DD) {
        int p = idx - DD * DD;
        float acc = w_b[p];
        #pragma unroll
        for (int o = 0; o < DD; ++o)
            acc = fmaf(w_w[p * DD + o], g_b[o], acc);
        Mc[idx] = acc;
    }
}

// ---------- K1 (d-parallel): 256-thr block = 32 pixels x 8 d-groups; grid 512.
// Each thread handles 8 d's of one pixel (<=4 f2v x-loads, 8 xf2 stores, 1 s8v
// xf_t store). ss reduced via LDS + 32-lane shfl. Fixes r25/r26's thin-grid prep
// (32 blocks, 60-deep serial loops). ----------
__global__ __launch_bounds__(256) void k_prep(const float* __restrict__ x,
                                              ushort* __restrict__ xf2,
                                              ushort* __restrict__ xf_t,
                                              float* __restrict__ rnorm,
                                              uint* __restrict__ mxbits) {
    __shared__ float ssp[8][33];
    int tid = threadIdx.x;
    int pix = tid & 31, j = tid >> 5;                  // d-group j: d = 8j..8j+7
    int n = blockIdx.x * 32 + pix;                     // blocks never cross b (128/batch)
    int b = n >> 12, nn = n & (NN - 1);
    int oh = nn >> 6, ow = nn & 63;
    const float* xb = x + (size_t)b * TC * HH * HH;
    ushort* x2 = xf2 + (size_t)b * DP * NN + nn;
    ushort row[8];
    float ss = 0.f;
    const int nh = (j < 7) ? 4 : 2;                    // j=7: only c1=14 (d 56..59)
    #pragma unroll
    for (int h = 0; h < 4; ++h) {
        if (h < nh) {
            int c1 = 2 * j + (h >> 1), r1 = h & 1;
            f2v v = *(const f2v*)&xb[(c1 * HH + oh * 2 + r1) * HH + ow * 2];
            ushort w0 = f2bf_bits(v[0]), w1 = f2bf_bits(v[1]);
            row[2 * h] = w0; row[2 * h + 1] = w1;
            float f0 = bf2f(w0), f1 = bf2f(w1);
            ss = fmaf(f0, f0, ss);
            ss = fmaf(f1, f1, ss);
            int d0 = 8 * j + 2 * h;
            x2[(size_t)d0 * NN] = w0;                  // 2x64B segments per instr
            x2[(size_t)(d0 + 1) * NN] = w1;
        } else {
            row[2 * h] = 0; row[2 * h + 1] = 0;        // xf_t padding d 60..63 = 0
        }
    }
    if (j == 7) {                                      // xf2 special rows
        x2[(size_t)60 * NN] = (ushort)0x3F80;          // ones row -> l accumulator
        x2[(size_t)61 * NN] = 0;
        x2[(size_t)62 * NN] = 0;
        x2[(size_t)63 * NN] = 0;
    }
    *(s8v*)&xf_t[(size_t)n * DP + j * 8] = *(const s8v*)row;

    ssp[j][pix] = ss;
    __syncthreads();
    if (tid < 32) {
        float tot = ssp[0][tid] + ssp[1][tid] + ssp[2][tid] + ssp[3][tid]
                  + ssp[4][tid] + ssp[5][tid] + ssp[6][tid] + ssp[7][tid];
        float norm = sqrtf(tot) * 1.0002f;             // safety margin: m bounds row max
        rnorm[blockIdx.x * 32 + tid] = norm;
        float mv = norm;
        #pragma unroll
        for (int off = 1; off < 32; off <<= 1) mv = fmaxf(mv, __shfl_xor(mv, off));
        if (tid == 0) atomicMax(&mxbits[b], __float_as_uint(mv));
    }
}

// ---------- K3: flash attention, split-K=4. Z = P.X^T with xf2 row 60 = 1 -> l.
// LDS single-buffer 24KB, 2 barriers/tile, reg-prefetch, P/PV interleave.
// m_n = rnorm[n]*mxnorm[b] fixed softmax shift (Cauchy-Schwarz upper bound).
// ALL NS write unnormalized Z (+l col); k_cout applies M and divides. UNCHANGED.
template <int NS>
__global__ __launch_bounds__(256, 2) void k_attn(const ushort* __restrict__ xf_t,
                                                 const ushort* __restrict__ x2_bf, // (B,64,N)
                                                 const float* __restrict__ rnorm,
                                                 const uint* __restrict__ mxbits,
                                                 ushort* __restrict__ O_bf) {  // (s,b,64,N) bf16
    __shared__ char K_lds[KT * 128];                   // 8 KB
    __shared__ char G_lds[DP * 128];                   // 8 KB (X^T tile)
    __shared__ char P_lds[NWAVE][16 * 128];            // 8 KB

    int p = blockIdx.x;
    int s, b, q0;
    if (NS == NSPLIT) {
        // XCD-aware: xcd = p&7; each XCD pair-half owns one batch (~1MB = L2-hot)
        int xcd = p & 7, slot = p >> 3;                // slot in [0,128)
        b = xcd >> 1;
        s = (xcd & 1) * 2 + (slot >> 6);               // NS=4: 2 splits per xcd-half
        q0 = (slot & 63) * QT;
    } else {
        s = 0;
        b = p >> 6;
        q0 = (p & 63) * QT;
    }
    int tid = threadIdx.x;
    int lane = tid & 63, wv = tid >> 6;
    int r = lane & 15, g = lane >> 4;

    const ushort* Xt = xf_t + (size_t)b * NN * DP;
    const ushort* Gb = x2_bf + (size_t)b * DP * NN;

    int qrow = q0 + wv * 16 + r;
    s8v qa[2];
    qa[0] = *(const s8v*)&Xt[(size_t)qrow * DP + g * 8];
    qa[1] = *(const s8v*)&Xt[(size_t)qrow * DP + 32 + g * 8];

    // fixed per-row shift, rows 4g+0..3 of this lane
    float mx = __uint_as_float(mxbits[b]);
    float nm[4];
    #pragma unroll
    for (int reg = 0; reg < 4; ++reg)
        nm[reg] = -rnorm[b * NN + q0 + wv * 16 + 4 * g + reg] * mx * L2E;

    f4v of[4];
    #pragma unroll
    for (int i = 0; i < 4; ++i) of[i] = (f4v){0.f, 0.f, 0.f, 0.f};

    // staging: 256 threads x two 16B units per buffer; row = e>>3, j = e&7
    const int e0 = tid, e1 = 256 + tid;
    const int kr0 = e0 >> 3, kj0 = e0 & 7;             // rows 0..31
    const int kr1 = e1 >> 3, kj1 = e1 & 7;             // rows 32..63
    const int kw0 = (kr0 * 128 + kj0 * 16) ^ ((kr0 & 7) << 4);
    const int kw1 = (kr1 * 128 + kj1 * 16) ^ ((kr1 & 7) << 4);
    s8v kp0, kp1, gp0, gp1;

    auto stage_regs = [&](int t) {
        int n0 = t * KT;
        kp0 = *(const s8v*)&Xt[(size_t)(n0 + kr0) * DP + kj0 * 8];
        kp1 = *(const s8v*)&Xt[(size_t)(n0 + kr1) * DP + kj1 * 8];
        gp0 = *(const s8v*)&Gb[(size_t)kr0 * NN + n0 + kj0 * 8];   // branch-free: 64 rows
        gp1 = *(const s8v*)&Gb[(size_t)kr1 * NN + n0 + kj1 * 8];
    };
    auto lds_write = [&]() {
        *(s8v*)(K_lds + kw0) = kp0;
        *(s8v*)(K_lds + kw1) = kp1;
        *(s8v*)(G_lds + kw0) = gp0;
        *(s8v*)(G_lds + kw1) = gp1;
    };

    const int t0 = s * (NTILES / NS);
    const int tend = t0 + NTILES / NS;
    char* Pw = P_lds[wv];

    stage_regs(t0);
    lds_write();
    __syncthreads();

    #pragma unroll 1
    for (int t = t0; t < tend; ++t) {
        bool more = (t + 1 < tend);
        if (more) stage_regs(t + 1);          // global loads in flight during compute

        // ---- S = Q.K^T ----
        f4v sf[4];
        #pragma unroll
        for (int i = 0; i < 4; ++i) sf[i] = (f4v){0.f, 0.f, 0.f, 0.f};
        #pragma unroll
        for (int kt2 = 0; kt2 < 4; ++kt2)
            #pragma unroll
            for (int kb = 0; kb < 2; ++kb) {
                int off = (((kt2 * 16 + r) * 128) + kb * 64 + g * 16) ^ ((r & 7) << 4);
                s8v bf = *(const s8v*)(K_lds + off);
                sf[kt2] = __builtin_amdgcn_mfma_f32_16x16x32_bf16(qa[kb], bf, sf[kt2], 0, 0, 0);
            }

        // ---- P for keys 0..31 (kt2 = 0,1), truncating cvt ----
        #pragma unroll
        for (int kt2 = 0; kt2 < 2; ++kt2)
            #pragma unroll
            for (int reg = 0; reg < 4; ++reg) {
                float pv = __builtin_exp2f(fmaf(sf[kt2][reg], L2E, nm[reg]));
                int row = 4 * g + reg;
                int boff = ((row * 128) + kt2 * 32 + 2 * r) ^ ((row & 7) << 4);
                *(ushort*)(Pw + boff) = f2bf_trunc(pv);
            }
        // ---- Z += P.X^T kb=0 (wave-internal LDS is in-order) ----
        {
            int poff = ((r * 128) + g * 16) ^ ((r & 7) << 4);
            s8v pa = *(const s8v*)(Pw + poff);
            #pragma unroll
            for (int ot = 0; ot < 4; ++ot) {
                int goff = (((ot * 16 + r) * 128) + g * 16) ^ ((r & 7) << 4);
                s8v gf = *(const s8v*)(G_lds + goff);
                of[ot] = __builtin_amdgcn_mfma_f32_16x16x32_bf16(pa, gf, of[ot], 0, 0, 0);
            }
        }
        // ---- P for keys 32..63 (kt2 = 2,3), truncating cvt ----
        #pragma unroll
        for (int kt2 = 2; kt2 < 4; ++kt2)
            #pragma unroll
            for (int reg = 0; reg < 4; ++reg) {
                float pv = __builtin_exp2f(fmaf(sf[kt2][reg], L2E, nm[reg]));
                int row = 4 * g + reg;
                int boff = ((row * 128) + kt2 * 32 + 2 * r) ^ ((row & 7) << 4);
                *(ushort*)(Pw + boff) = f2bf_trunc(pv);
            }
        // ---- Z += P.X^T kb=1 ----
        {
            int poff = ((r * 128) + 64 + g * 16) ^ ((r & 7) << 4);
            s8v pa = *(const s8v*)(Pw + poff);
            #pragma unroll
            for (int ot = 0; ot < 4; ++ot) {
                int goff = (((ot * 16 + r) * 128) + 64 + g * 16) ^ ((r & 7) << 4);
                s8v gf = *(const s8v*)(G_lds + goff);
                of[ot] = __builtin_amdgcn_mfma_f32_16x16x32_bf16(pa, gf, of[ot], 0, 0, 0);
            }
        }

        if (more) {
            __syncthreads();                  // all waves done reading K/X^T
            lds_write();
            __syncthreads();                  // next tile staged
        }
    }

    // epilogue: unnormalized Z (+ l in col 60); k_cout applies M and divides
    int qb = q0 + wv * 16 + 4 * g;
    ushort* Ob = O_bf + ((size_t)(s * BB + b) * DP) * NN;
    #pragma unroll
    for (int ot = 0; ot < 4; ++ot) {
        int o = ot * 16 + r;
        u4v v = {f2bf_bits(of[ot][0]), f2bf_bits(of[ot][1]),
                 f2bf_bits(of[ot][2]), f2bf_bits(of[ot][3])};
        *(u4v*)&Ob[(size_t)o * NN + qb] = v;                 // coalesced 32B per r-group
    }
}

// ---------- K4 (fused combine+out): proven r24 version (block per 32 pixels,
// grid BB*128, 8 outputs/thread). Phase 1: sum NS splits into z_lds[32][61] f32
// + linv from l col (o=60). Phase 2: out[p] = (M[p].z)*linv + c[p] + x.
template <int NS>
__global__ __launch_bounds__(256) void k_cout(const ushort* __restrict__ O_bf,
                                              const float* __restrict__ Mc,
                                              const float* __restrict__ x,
                                              float* __restrict__ out) {
    __shared__ float ww[DD * DD];                      // 14.4 KB (= M)
    __shared__ float wb[DD];                           //          (= c)
    __shared__ float zlds[32][61];                     // 7.8 KB
    __shared__ float linv[32];

    int b  = blockIdx.x >> 7;                          // grid = BB*128
    int n0 = (blockIdx.x & 127) * 32;
    int tid = threadIdx.x;
    for (int i = tid; i < DD * DD; i += 256) ww[i] = Mc[i];
    if (tid < DD) wb[tid] = Mc[DD * DD + tid];

    int pix  = tid & 31;
    int ogrp = tid >> 5;                               // 0..7
    int n = n0 + pix;

    // ---- phase 1: z[pix][d] = sum_s Z_s[d][n] ; linv[pix] = 1/sum_s Z_s[60][n] ----
    const ushort* Op = O_bf + (size_t)b * DP * NN + n;
    #pragma unroll
    for (int i = 0; i < 8; ++i) {
        int o = ogrp * 8 + i;                          // 0..63
        if (o > DD) continue;                          // o<=60 processed
        float sum = 0.f;
        #pragma unroll
        for (int ss = 0; ss < NS; ++ss)
            sum += bf2f(Op[(size_t)ss * BB * DP * NN + (size_t)o * NN]);
        if (o < DD) zlds[pix][o] = sum;
        else        linv[pix] = 1.0f / sum;            // o == 60
    }
    __syncthreads();

    // ---- phase 2: 8 outputs per thread (p = 8k+ogrp), M from LDS, z from LDS ----
    float li = linv[pix];
    int oh = n >> 6, ow = n & 63;
    #pragma unroll
    for (int k = 0; k < 8; ++k) {
        int o = k * 8 + ogrp;
        if (o < DD) {
            float acc = 0.f;
            #pragma unroll
            for (int d = 0; d < DD; ++d)
                acc = fmaf(ww[o * DD + d], zlds[pix][d], acc);
            int c1 = o >> 2, r1 = (o >> 1) & 1, r2 = o & 1;
            size_t xi = ((size_t)(b * TC + c1) * HH + 2 * oh + r1) * HH + 2 * ow + r2;
            out[xi] = fmaf(acc, li, wb[o]) + x[xi];
        }
    }
}

extern "C" void kernel_launch(void* const* d_in, const int* in_sizes, int n_in,
                              void* d_out, int out_size, void* d_ws, size_t ws_size,
                              hipStream_t stream) {
    const float* x   = (const float*)d_in[0];
    const float* g_w = (const float*)d_in[1];
    const float* g_b = (const float*)d_in[2];
    const float* w_w = (const float*)d_in[3];
    const float* w_b = (const float*)d_in[4];
    float* out = (float*)d_out;

    char* ws = (char*)d_ws;
    ushort* xf2    = (ushort*)ws;                      // 2,097,152 B (B,64,N)
    ushort* xf_t   = (ushort*)(ws + 2097152);          // 2,097,152 B (B,N,64)
    float*  rnorm  = (float*)(ws + 4194304);           // 65,536 B
    uint*   mxbits = (uint*)(ws + 4259840);            // 256 B
    float*  Mc     = (float*)(ws + 4260096);           // 16,384 B  (3600 M + 60 c)
    ushort* O_bf   = (ushort*)(ws + 4276480);          // 8,388,608 B (NS=4) -> end 12,665,088
    const size_t SPLIT_NEED = 12665088;

    k_mw<<<16, 256, 0, stream>>>(g_w, g_b, w_w, w_b, Mc, mxbits);  // also zeroes mxbits
    k_prep<<<BB * NN / 32, 256, 0, stream>>>(x, xf2, xf_t, rnorm, mxbits);

    if (ws_size >= SPLIT_NEED) {
        k_attn<NSPLIT><<<NSPLIT * BB * (NN / QT), 256, 0, stream>>>(
            xf_t, xf2, rnorm, mxbits, O_bf);
        k_cout<NSPLIT><<<BB * 128, 256, 0, stream>>>(O_bf, Mc, x, out);
    } else {
        k_attn<1><<<BB * (NN / QT), 256, 0, stream>>>(
            xf_t, xf2, rnorm, mxbits, O_bf);
        k_cout<1><<<BB * 128, 256, 0, stream>>>(O_bf, Mc, x, out);
    }
}

// Round 28
// 68.313 us; speedup vs baseline: 1.2837x; 1.0336x over previous
//
#include <hip/hip_runtime.h>
#include <hip/hip_bf16.h>

// x: (B=4, T=5, C=3, H=128, W=128) fp32 ; R=2 ; D = 60 ; N = 4096
#define BB 4
#define TC 15
#define DD 60
#define NN 4096
#define HH 128
#define DP 64
#define KT 64
#define NWAVE 4
#define QT 64
#define NTILES 64
#define NSPLIT 4
#define L2E 1.4426950408889634f

typedef short s8v __attribute__((ext_vector_type(8)));   // 8 x bf16
typedef ushort u4v __attribute__((ext_vector_type(4)));
typedef uint  uu2 __attribute__((ext_vector_type(2)));
typedef float f4v __attribute__((ext_vector_type(4)));
typedef float f2v __attribute__((ext_vector_type(2)));

static __device__ __forceinline__ ushort f2bf_bits(float f) {
    __hip_bfloat16 h = __float2bfloat16(f);
    return *reinterpret_cast<ushort*>(&h);
}
static __device__ __forceinline__ float bf2f(ushort w) { return __uint_as_float((uint)w << 16); }

// ---------- K0 (tiny, launched FIRST): zero mxbits + M = w_w.g_w ; c = w_w.g_b + w_b ----------
// Algebra: out = w_w.Y + w_b with Y = (Z/l).g_w^T + g_b^T  ==>  out = (Z/l).M^T + c.
__global__ __launch_bounds__(256) void k_mw(const float* __restrict__ g_w,
                                            const float* __restrict__ g_b,
                                            const float* __restrict__ w_w,
                                            const float* __restrict__ w_b,
                                            float* __restrict__ Mc,     // [3600 M][60 c]
                                            uint* __restrict__ mxbits) {
    int idx = blockIdx.x * 256 + threadIdx.x;
    if (idx < BB) mxbits[idx] = 0;                     // same-stream: done before k_prep
    if (idx < DD * DD) {
        int p = idx / DD, d = idx % DD;
        float acc = 0.f;
        #pragma unroll
        for (int o = 0; o < DD; ++o)
            acc = fmaf(w_w[p * DD + o], g_w[o * DD + d], acc);
        Mc[idx] = acc;
    } else if (idx < DD * DD + DD) {
        int p = idx - DD * DD;
        float acc = w_b[p];
        #pragma unroll
        for (int o = 0; o < DD; ++o)
            acc = fmaf(w_w[p * DD + o], g_b[o], acc);
        Mc[idx] = acc;
    }
}

// ---------- K1 (d-parallel): 256-thr block = 32 pixels x 8 d-groups; grid 512. ----------
__global__ __launch_bounds__(256) void k_prep(const float* __restrict__ x,
                                              ushort* __restrict__ xf2,
                                              ushort* __restrict__ xf_t,
                                              float* __restrict__ rnorm,
                                              uint* __restrict__ mxbits) {
    __shared__ float ssp[8][33];
    int tid = threadIdx.x;
    int pix = tid & 31, j = tid >> 5;                  // d-group j: d = 8j..8j+7
    int n = blockIdx.x * 32 + pix;                     // blocks never cross b (128/batch)
    int b = n >> 12, nn = n & (NN - 1);
    int oh = nn >> 6, ow = nn & 63;
    const float* xb = x + (size_t)b * TC * HH * HH;
    ushort* x2 = xf2 + (size_t)b * DP * NN + nn;
    ushort row[8];
    float ss = 0.f;
    const int nh = (j < 7) ? 4 : 2;                    // j=7: only c1=14 (d 56..59)
    #pragma unroll
    for (int h = 0; h < 4; ++h) {
        if (h < nh) {
            int c1 = 2 * j + (h >> 1), r1 = h & 1;
            f2v v = *(const f2v*)&xb[(c1 * HH + oh * 2 + r1) * HH + ow * 2];
            ushort w0 = f2bf_bits(v[0]), w1 = f2bf_bits(v[1]);
            row[2 * h] = w0; row[2 * h + 1] = w1;
            float f0 = bf2f(w0), f1 = bf2f(w1);
            ss = fmaf(f0, f0, ss);
            ss = fmaf(f1, f1, ss);
            int d0 = 8 * j + 2 * h;
            x2[(size_t)d0 * NN] = w0;
            x2[(size_t)(d0 + 1) * NN] = w1;
        } else {
            row[2 * h] = 0; row[2 * h + 1] = 0;        // xf_t padding d 60..63 = 0
        }
    }
    if (j == 7) {                                      // xf2 special rows
        x2[(size_t)60 * NN] = (ushort)0x3F80;          // ones row -> l accumulator
        x2[(size_t)61 * NN] = 0;
        x2[(size_t)62 * NN] = 0;
        x2[(size_t)63 * NN] = 0;
    }
    *(s8v*)&xf_t[(size_t)n * DP + j * 8] = *(const s8v*)row;

    ssp[j][pix] = ss;
    __syncthreads();
    if (tid < 32) {
        float tot = ssp[0][tid] + ssp[1][tid] + ssp[2][tid] + ssp[3][tid]
                  + ssp[4][tid] + ssp[5][tid] + ssp[6][tid] + ssp[7][tid];
        float norm = sqrtf(tot) * 1.0002f;             // safety margin: m bounds row max
        rnorm[blockIdx.x * 32 + tid] = norm;
        float mv = norm;
        #pragma unroll
        for (int off = 1; off < 32; off <<= 1) mv = fmaxf(mv, __shfl_xor(mv, off));
        if (tid == 0) atomicMax(&mxbits[b], __float_as_uint(mv));
    }
}

// ---------- K3: flash attention, split-K=4, SWAPPED-OPERAND QK^T.
// S^T = mfma(K_frag, Q_frag): lane holds S[query=r][key=16*kt2+4g+reg] -> nm is a
// single scalar (query lane-fixed), and each kt2's 4 P values are CONSECUTIVE keys:
// pack 2 truncated bf16/dword, ONE ds_write_b64 per kt2 (4 b64 vs 16 b16 + XOR calcs).
// Write addr (r*128 + 32kt2 + 8g)^((r&7)<<4) lands exactly where the unchanged pa
// read expects. PV, epilogue, staging, barriers byte-identical to r27.
// Z = P.X^T with xf2 row 60 = 1 -> l. k_cout applies M and divides.
template <int NS>
__global__ __launch_bounds__(256, 2) void k_attn(const ushort* __restrict__ xf_t,
                                                 const ushort* __restrict__ x2_bf, // (B,64,N)
                                                 const float* __restrict__ rnorm,
                                                 const uint* __restrict__ mxbits,
                                                 ushort* __restrict__ O_bf) {  // (s,b,64,N) bf16
    __shared__ char K_lds[KT * 128];                   // 8 KB
    __shared__ char G_lds[DP * 128];                   // 8 KB (X^T tile)
    __shared__ char P_lds[NWAVE][16 * 128];            // 8 KB

    int p = blockIdx.x;
    int s, b, q0;
    if (NS == NSPLIT) {
        // XCD-aware: xcd = p&7; each XCD pair-half owns one batch (~1MB = L2-hot)
        int xcd = p & 7, slot = p >> 3;                // slot in [0,128)
        b = xcd >> 1;
        s = (xcd & 1) * 2 + (slot >> 6);               // NS=4: 2 splits per xcd-half
        q0 = (slot & 63) * QT;
    } else {
        s = 0;
        b = p >> 6;
        q0 = (p & 63) * QT;
    }
    int tid = threadIdx.x;
    int lane = tid & 63, wv = tid >> 6;
    int r = lane & 15, g = lane >> 4;

    const ushort* Xt = xf_t + (size_t)b * NN * DP;
    const ushort* Gb = x2_bf + (size_t)b * DP * NN;

    int qrow = q0 + wv * 16 + r;
    s8v qa[2];
    qa[0] = *(const s8v*)&Xt[(size_t)qrow * DP + g * 8];
    qa[1] = *(const s8v*)&Xt[(size_t)qrow * DP + 32 + g * 8];

    // fixed softmax shift: query is lane-fixed (= r) -> ONE scalar
    float mx = __uint_as_float(mxbits[b]);
    float nm = -rnorm[b * NN + qrow] * mx * L2E;

    f4v of[4];
    #pragma unroll
    for (int i = 0; i < 4; ++i) of[i] = (f4v){0.f, 0.f, 0.f, 0.f};

    // staging: 256 threads x two 16B units per buffer; row = e>>3, j = e&7
    const int e0 = tid, e1 = 256 + tid;
    const int kr0 = e0 >> 3, kj0 = e0 & 7;             // rows 0..31
    const int kr1 = e1 >> 3, kj1 = e1 & 7;             // rows 32..63
    const int kw0 = (kr0 * 128 + kj0 * 16) ^ ((kr0 & 7) << 4);
    const int kw1 = (kr1 * 128 + kj1 * 16) ^ ((kr1 & 7) << 4);
    s8v kp0, kp1, gp0, gp1;

    auto stage_regs = [&](int t) {
        int n0 = t * KT;
        kp0 = *(const s8v*)&Xt[(size_t)(n0 + kr0) * DP + kj0 * 8];
        kp1 = *(const s8v*)&Xt[(size_t)(n0 + kr1) * DP + kj1 * 8];
        gp0 = *(const s8v*)&Gb[(size_t)kr0 * NN + n0 + kj0 * 8];   // branch-free: 64 rows
        gp1 = *(const s8v*)&Gb[(size_t)kr1 * NN + n0 + kj1 * 8];
    };
    auto lds_write = [&]() {
        *(s8v*)(K_lds + kw0) = kp0;
        *(s8v*)(K_lds + kw1) = kp1;
        *(s8v*)(G_lds + kw0) = gp0;
        *(s8v*)(G_lds + kw1) = gp1;
    };

    const int t0 = s * (NTILES / NS);
    const int tend = t0 + NTILES / NS;
    char* Pw = P_lds[wv];

    stage_regs(t0);
    lds_write();
    __syncthreads();

    #pragma unroll 1
    for (int t = t0; t < tend; ++t) {
        bool more = (t + 1 < tend);
        if (more) stage_regs(t + 1);          // global loads in flight during compute

        // ---- S^T = K.Q^T (swapped operands; same LDS reads) ----
        f4v sf[4];
        #pragma unroll
        for (int i = 0; i < 4; ++i) sf[i] = (f4v){0.f, 0.f, 0.f, 0.f};
        #pragma unroll
        for (int kt2 = 0; kt2 < 4; ++kt2)
            #pragma unroll
            for (int kb = 0; kb < 2; ++kb) {
                int off = (((kt2 * 16 + r) * 128) + kb * 64 + g * 16) ^ ((r & 7) << 4);
                s8v bf = *(const s8v*)(K_lds + off);
                sf[kt2] = __builtin_amdgcn_mfma_f32_16x16x32_bf16(bf, qa[kb], sf[kt2], 0, 0, 0);
            }

        // ---- P keys 0..31 (kt2 = 0,1): 4 exp2 -> 2 packed dwords -> 1 b64 write ----
        #pragma unroll
        for (int kt2 = 0; kt2 < 2; ++kt2) {
            uint p0 = __float_as_uint(__builtin_exp2f(fmaf(sf[kt2][0], L2E, nm)));
            uint p1 = __float_as_uint(__builtin_exp2f(fmaf(sf[kt2][1], L2E, nm)));
            uint p2 = __float_as_uint(__builtin_exp2f(fmaf(sf[kt2][2], L2E, nm)));
            uint p3 = __float_as_uint(__builtin_exp2f(fmaf(sf[kt2][3], L2E, nm)));
            uu2 dw = { (p0 >> 16) | (p1 & 0xFFFF0000u),
                       (p2 >> 16) | (p3 & 0xFFFF0000u) };
            int woff = ((r * 128) + 32 * kt2 + 8 * g) ^ ((r & 7) << 4);
            *(uu2*)(Pw + woff) = dw;
        }
        // ---- Z += P.X^T kb=0 (wave-internal LDS is in-order) ----
        {
            int poff = ((r * 128) + g * 16) ^ ((r & 7) << 4);
            s8v pa = *(const s8v*)(Pw + poff);
            #pragma unroll
            for (int ot = 0; ot < 4; ++ot) {
                int goff = (((ot * 16 + r) * 128) + g * 16) ^ ((r & 7) << 4);
                s8v gf = *(const s8v*)(G_lds + goff);
                of[ot] = __builtin_amdgcn_mfma_f32_16x16x32_bf16(pa, gf, of[ot], 0, 0, 0);
            }
        }
        // ---- P keys 32..63 (kt2 = 2,3) ----
        #pragma unroll
        for (int kt2 = 2; kt2 < 4; ++kt2) {
            uint p0 = __float_as_uint(__builtin_exp2f(fmaf(sf[kt2][0], L2E, nm)));
            uint p1 = __float_as_uint(__builtin_exp2f(fmaf(sf[kt2][1], L2E, nm)));
            uint p2 = __float_as_uint(__builtin_exp2f(fmaf(sf[kt2][2], L2E, nm)));
            uint p3 = __float_as_uint(__builtin_exp2f(fmaf(sf[kt2][3], L2E, nm)));
            uu2 dw = { (p0 >> 16) | (p1 & 0xFFFF0000u),
                       (p2 >> 16) | (p3 & 0xFFFF0000u) };
            int woff = ((r * 128) + 32 * kt2 + 8 * g) ^ ((r & 7) << 4);
            *(uu2*)(Pw + woff) = dw;
        }
        // ---- Z += P.X^T kb=1 ----
        {
            int poff = ((r * 128) + 64 + g * 16) ^ ((r & 7) << 4);
            s8v pa = *(const s8v*)(Pw + poff);
            #pragma unroll
            for (int ot = 0; ot < 4; ++ot) {
                int goff = (((ot * 16 + r) * 128) + 64 + g * 16) ^ ((r & 7) << 4);
                s8v gf = *(const s8v*)(G_lds + goff);
                of[ot] = __builtin_amdgcn_mfma_f32_16x16x32_bf16(pa, gf, of[ot], 0, 0, 0);
            }
        }

        if (more) {
            __syncthreads();                  // all waves done reading K/X^T
            lds_write();
            __syncthreads();                  // next tile staged
        }
    }

    // epilogue: unnormalized Z (+ l in col 60); k_cout applies M and divides
    int qb = q0 + wv * 16 + 4 * g;
    ushort* Ob = O_bf + ((size_t)(s * BB + b) * DP) * NN;
    #pragma unroll
    for (int ot = 0; ot < 4; ++ot) {
        int o = ot * 16 + r;
        u4v v = {f2bf_bits(of[ot][0]), f2bf_bits(of[ot][1]),
                 f2bf_bits(of[ot][2]), f2bf_bits(of[ot][3])};
        *(u4v*)&Ob[(size_t)o * NN + qb] = v;                 // coalesced 32B per r-group
    }
}

// ---------- K4 (fused combine+out): proven r24 version (block per 32 pixels,
// grid BB*128, 8 outputs/thread). Phase 1: sum NS splits into z_lds[32][61] f32
// + linv from l col (o=60). Phase 2: out[p] = (M[p].z)*linv + c[p] + x.
template <int NS>
__global__ __launch_bounds__(256) void k_cout(const ushort* __restrict__ O_bf,
                                              const float* __restrict__ Mc,
                                              const float* __restrict__ x,
                                              float* __restrict__ out) {
    __shared__ float ww[DD * DD];                      // 14.4 KB (= M)
    __shared__ float wb[DD];                           //          (= c)
    __shared__ float zlds[32][61];                     // 7.8 KB
    __shared__ float linv[32];

    int b  = blockIdx.x >> 7;                          // grid = BB*128
    int n0 = (blockIdx.x & 127) * 32;
    int tid = threadIdx.x;
    for (int i = tid; i < DD * DD; i += 256) ww[i] = Mc[i];
    if (tid < DD) wb[tid] = Mc[DD * DD + tid];

    int pix  = tid & 31;
    int ogrp = tid >> 5;                               // 0..7
    int n = n0 + pix;

    // ---- phase 1: z[pix][d] = sum_s Z_s[d][n] ; linv[pix] = 1/sum_s Z_s[60][n] ----
    const ushort* Op = O_bf + (size_t)b * DP * NN + n;
    #pragma unroll
    for (int i = 0; i < 8; ++i) {
        int o = ogrp * 8 + i;                          // 0..63
        if (o > DD) continue;                          // o<=60 processed
        float sum = 0.f;
        #pragma unroll
        for (int ss = 0; ss < NS; ++ss)
            sum += bf2f(Op[(size_t)ss * BB * DP * NN + (size_t)o * NN]);
        if (o < DD) zlds[pix][o] = sum;
        else        linv[pix] = 1.0f / sum;            // o == 60
    }
    __syncthreads();

    // ---- phase 2: 8 outputs per thread (p = 8k+ogrp), M from LDS, z from LDS ----
    float li = linv[pix];
    int oh = n >> 6, ow = n & 63;
    #pragma unroll
    for (int k = 0; k < 8; ++k) {
        int o = k * 8 + ogrp;
        if (o < DD) {
            float acc = 0.f;
            #pragma unroll
            for (int d = 0; d < DD; ++d)
                acc = fmaf(ww[o * DD + d], zlds[pix][d], acc);
            int c1 = o >> 2, r1 = (o >> 1) & 1, r2 = o & 1;
            size_t xi = ((size_t)(b * TC + c1) * HH + 2 * oh + r1) * HH + 2 * ow + r2;
            out[xi] = fmaf(acc, li, wb[o]) + x[xi];
        }
    }
}

extern "C" void kernel_launch(void* const* d_in, const int* in_sizes, int n_in,
                              void* d_out, int out_size, void* d_ws, size_t ws_size,
                              hipStream_t stream) {
    const float* x   = (const float*)d_in[0];
    const float* g_w = (const float*)d_in[1];
    const float* g_b = (const float*)d_in[2];
    const float* w_w = (const float*)d_in[3];
    const float* w_b = (const float*)d_in[4];
    float* out = (float*)d_out;

    char* ws = (char*)d_ws;
    ushort* xf2    = (ushort*)ws;                      // 2,097,152 B (B,64,N)
    ushort* xf_t   = (ushort*)(ws + 2097152);          // 2,097,152 B (B,N,64)
    float*  rnorm  = (float*)(ws + 4194304);           // 65,536 B
    uint*   mxbits = (uint*)(ws + 4259840);            // 256 B
    float*  Mc     = (float*)(ws + 4260096);           // 16,384 B  (3600 M + 60 c)
    ushort* O_bf   = (ushort*)(ws + 4276480);          // 8,388,608 B (NS=4) -> end 12,665,088
    const size_t SPLIT_NEED = 12665088;

    k_mw<<<16, 256, 0, stream>>>(g_w, g_b, w_w, w_b, Mc, mxbits);  // also zeroes mxbits
    k_prep<<<BB * NN / 32, 256, 0, stream>>>(x, xf2, xf_t, rnorm, mxbits);

    if (ws_size >= SPLIT_NEED) {
        k_attn<NSPLIT><<<NSPLIT * BB * (NN / QT), 256, 0, stream>>>(
            xf_t, xf2, rnorm, mxbits, O_bf);
        k_cout<NSPLIT><<<BB * 128, 256, 0, stream>>>(O_bf, Mc, x, out);
    } else {
        k_attn<1><<<BB * (NN / QT), 256, 0, stream>>>(
            xf_t, xf2, rnorm, mxbits, O_bf);
        k_cout<1><<<BB * 128, 256, 0, stream>>>(O_bf, Mc, x, out);
    }
}

// Round 29
// 65.742 us; speedup vs baseline: 1.3339x; 1.0391x over previous
//
#include <hip/hip_runtime.h>
#include <hip/hip_bf16.h>

// x: (B=4, T=5, C=3, H=128, W=128) fp32 ; R=2 ; D = 60 ; N = 4096
#define BB 4
#define TC 15
#define DD 60
#define NN 4096
#define HH 128
#define DP 64
#define KT 64
#define NWAVE 4
#define QT 64
#define NTILES 64
#define NSPLIT 4
#define L2E 1.4426950408889634f

typedef short s8v __attribute__((ext_vector_type(8)));   // 8 x bf16
typedef ushort u4v __attribute__((ext_vector_type(4)));
typedef uint  uu2 __attribute__((ext_vector_type(2)));
typedef float f4v __attribute__((ext_vector_type(4)));
typedef float f2v __attribute__((ext_vector_type(2)));

static __device__ __forceinline__ ushort f2bf_bits(float f) {
    __hip_bfloat16 h = __float2bfloat16(f);
    return *reinterpret_cast<ushort*>(&h);
}
static __device__ __forceinline__ float bf2f(ushort w) { return __uint_as_float((uint)w << 16); }
static __device__ __forceinline__ float bf2f_lo(uint u) { return __uint_as_float(u << 16); }
static __device__ __forceinline__ float bf2f_hi(uint u) { return __uint_as_float(u & 0xFFFF0000u); }

// ---------- K0 (tiny, launched FIRST): zero mxbits + M = w_w.g_w ; c = w_w.g_b + w_b ----------
// Algebra: out = w_w.Y + w_b with Y = (Z/l).g_w^T + g_b^T  ==>  out = (Z/l).M^T + c.
__global__ __launch_bounds__(256) void k_mw(const float* __restrict__ g_w,
                                            const float* __restrict__ g_b,
                                            const float* __restrict__ w_w,
                                            const float* __restrict__ w_b,
                                            float* __restrict__ Mc,     // [3600 M][60 c]
                                            uint* __restrict__ mxbits) {
    int idx = blockIdx.x * 256 + threadIdx.x;
    if (idx < BB) mxbits[idx] = 0;                     // same-stream: done before k_prep
    if (idx < DD * DD) {
        int p = idx / DD, d = idx % DD;
        float acc = 0.f;
        #pragma unroll
        for (int o = 0; o < DD; ++o)
            acc = fmaf(w_w[p * DD + o], g_w[o * DD + d], acc);
        Mc[idx] = acc;
    } else if (idx < DD * DD + DD) {
        int p = idx - DD * DD;
        float acc = w_b[p];
        #pragma unroll
        for (int o = 0; o < DD; ++o)
            acc = fmaf(w_w[p * DD + o], g_b[o], acc);
        Mc[idx] = acc;
    }
}

// ---------- K1 (d-parallel): 256-thr block = 32 pixels x 8 d-groups; grid 512. ----------
__global__ __launch_bounds__(256) void k_prep(const float* __restrict__ x,
                                              ushort* __restrict__ xf2,
                                              ushort* __restrict__ xf_t,
                                              float* __restrict__ rnorm,
                                              uint* __restrict__ mxbits) {
    __shared__ float ssp[8][33];
    int tid = threadIdx.x;
    int pix = tid & 31, j = tid >> 5;                  // d-group j: d = 8j..8j+7
    int n = blockIdx.x * 32 + pix;                     // blocks never cross b (128/batch)
    int b = n >> 12, nn = n & (NN - 1);
    int oh = nn >> 6, ow = nn & 63;
    const float* xb = x + (size_t)b * TC * HH * HH;
    ushort* x2 = xf2 + (size_t)b * DP * NN + nn;
    ushort row[8];
    float ss = 0.f;
    const int nh = (j < 7) ? 4 : 2;                    // j=7: only c1=14 (d 56..59)
    #pragma unroll
    for (int h = 0; h < 4; ++h) {
        if (h < nh) {
            int c1 = 2 * j + (h >> 1), r1 = h & 1;
            f2v v = *(const f2v*)&xb[(c1 * HH + oh * 2 + r1) * HH + ow * 2];
            ushort w0 = f2bf_bits(v[0]), w1 = f2bf_bits(v[1]);
            row[2 * h] = w0; row[2 * h + 1] = w1;
            float f0 = bf2f(w0), f1 = bf2f(w1);
            ss = fmaf(f0, f0, ss);
            ss = fmaf(f1, f1, ss);
            int d0 = 8 * j + 2 * h;
            x2[(size_t)d0 * NN] = w0;
            x2[(size_t)(d0 + 1) * NN] = w1;
        } else {
            row[2 * h] = 0; row[2 * h + 1] = 0;        // xf_t padding d 60..63 = 0
        }
    }
    if (j == 7) {                                      // xf2 special rows
        x2[(size_t)60 * NN] = (ushort)0x3F80;          // ones row -> l accumulator
        x2[(size_t)61 * NN] = 0;
        x2[(size_t)62 * NN] = 0;
        x2[(size_t)63 * NN] = 0;
    }
    *(s8v*)&xf_t[(size_t)n * DP + j * 8] = *(const s8v*)row;

    ssp[j][pix] = ss;
    __syncthreads();
    if (tid < 32) {
        float tot = ssp[0][tid] + ssp[1][tid] + ssp[2][tid] + ssp[3][tid]
                  + ssp[4][tid] + ssp[5][tid] + ssp[6][tid] + ssp[7][tid];
        float norm = sqrtf(tot) * 1.0002f;             // safety margin: m bounds row max
        rnorm[blockIdx.x * 32 + tid] = norm;
        float mv = norm;
        #pragma unroll
        for (int off = 1; off < 32; off <<= 1) mv = fmaxf(mv, __shfl_xor(mv, off));
        if (tid == 0) atomicMax(&mxbits[b], __float_as_uint(mv));
    }
}

// ---------- K3: flash attention, split-K=4, SWAPPED-OPERAND QK^T (r28 proven).
// S^T = mfma(K_frag, Q_frag): lane holds S[query=r][key=16*kt2+4g+reg]; nm scalar;
// 4 packed b64 P-writes per tile (bank cost is data-volume-intrinsic).
// Z = P.X^T with xf2 row 60 = 1 -> l. k_cout applies M and divides. UNCHANGED.
template <int NS>
__global__ __launch_bounds__(256, 2) void k_attn(const ushort* __restrict__ xf_t,
                                                 const ushort* __restrict__ x2_bf, // (B,64,N)
                                                 const float* __restrict__ rnorm,
                                                 const uint* __restrict__ mxbits,
                                                 ushort* __restrict__ O_bf) {  // (s,b,64,N) bf16
    __shared__ char K_lds[KT * 128];                   // 8 KB
    __shared__ char G_lds[DP * 128];                   // 8 KB (X^T tile)
    __shared__ char P_lds[NWAVE][16 * 128];            // 8 KB

    int p = blockIdx.x;
    int s, b, q0;
    if (NS == NSPLIT) {
        // XCD-aware: xcd = p&7; each XCD pair-half owns one batch (~1MB = L2-hot)
        int xcd = p & 7, slot = p >> 3;                // slot in [0,128)
        b = xcd >> 1;
        s = (xcd & 1) * 2 + (slot >> 6);               // NS=4: 2 splits per xcd-half
        q0 = (slot & 63) * QT;
    } else {
        s = 0;
        b = p >> 6;
        q0 = (p & 63) * QT;
    }
    int tid = threadIdx.x;
    int lane = tid & 63, wv = tid >> 6;
    int r = lane & 15, g = lane >> 4;

    const ushort* Xt = xf_t + (size_t)b * NN * DP;
    const ushort* Gb = x2_bf + (size_t)b * DP * NN;

    int qrow = q0 + wv * 16 + r;
    s8v qa[2];
    qa[0] = *(const s8v*)&Xt[(size_t)qrow * DP + g * 8];
    qa[1] = *(const s8v*)&Xt[(size_t)qrow * DP + 32 + g * 8];

    // fixed softmax shift: query is lane-fixed (= r) -> ONE scalar
    float mx = __uint_as_float(mxbits[b]);
    float nm = -rnorm[b * NN + qrow] * mx * L2E;

    f4v of[4];
    #pragma unroll
    for (int i = 0; i < 4; ++i) of[i] = (f4v){0.f, 0.f, 0.f, 0.f};

    // staging: 256 threads x two 16B units per buffer; row = e>>3, j = e&7
    const int e0 = tid, e1 = 256 + tid;
    const int kr0 = e0 >> 3, kj0 = e0 & 7;             // rows 0..31
    const int kr1 = e1 >> 3, kj1 = e1 & 7;             // rows 32..63
    const int kw0 = (kr0 * 128 + kj0 * 16) ^ ((kr0 & 7) << 4);
    const int kw1 = (kr1 * 128 + kj1 * 16) ^ ((kr1 & 7) << 4);
    s8v kp0, kp1, gp0, gp1;

    auto stage_regs = [&](int t) {
        int n0 = t * KT;
        kp0 = *(const s8v*)&Xt[(size_t)(n0 + kr0) * DP + kj0 * 8];
        kp1 = *(const s8v*)&Xt[(size_t)(n0 + kr1) * DP + kj1 * 8];
        gp0 = *(const s8v*)&Gb[(size_t)kr0 * NN + n0 + kj0 * 8];   // branch-free: 64 rows
        gp1 = *(const s8v*)&Gb[(size_t)kr1 * NN + n0 + kj1 * 8];
    };
    auto lds_write = [&]() {
        *(s8v*)(K_lds + kw0) = kp0;
        *(s8v*)(K_lds + kw1) = kp1;
        *(s8v*)(G_lds + kw0) = gp0;
        *(s8v*)(G_lds + kw1) = gp1;
    };

    const int t0 = s * (NTILES / NS);
    const int tend = t0 + NTILES / NS;
    char* Pw = P_lds[wv];

    stage_regs(t0);
    lds_write();
    __syncthreads();

    #pragma unroll 1
    for (int t = t0; t < tend; ++t) {
        bool more = (t + 1 < tend);
        if (more) stage_regs(t + 1);          // global loads in flight during compute

        // ---- S^T = K.Q^T (swapped operands; same LDS reads) ----
        f4v sf[4];
        #pragma unroll
        for (int i = 0; i < 4; ++i) sf[i] = (f4v){0.f, 0.f, 0.f, 0.f};
        #pragma unroll
        for (int kt2 = 0; kt2 < 4; ++kt2)
            #pragma unroll
            for (int kb = 0; kb < 2; ++kb) {
                int off = (((kt2 * 16 + r) * 128) + kb * 64 + g * 16) ^ ((r & 7) << 4);
                s8v bf = *(const s8v*)(K_lds + off);
                sf[kt2] = __builtin_amdgcn_mfma_f32_16x16x32_bf16(bf, qa[kb], sf[kt2], 0, 0, 0);
            }

        // ---- P keys 0..31 (kt2 = 0,1): 4 exp2 -> 2 packed dwords -> 1 b64 write ----
        #pragma unroll
        for (int kt2 = 0; kt2 < 2; ++kt2) {
            uint p0 = __float_as_uint(__builtin_exp2f(fmaf(sf[kt2][0], L2E, nm)));
            uint p1 = __float_as_uint(__builtin_exp2f(fmaf(sf[kt2][1], L2E, nm)));
            uint p2 = __float_as_uint(__builtin_exp2f(fmaf(sf[kt2][2], L2E, nm)));
            uint p3 = __float_as_uint(__builtin_exp2f(fmaf(sf[kt2][3], L2E, nm)));
            uu2 dw = { (p0 >> 16) | (p1 & 0xFFFF0000u),
                       (p2 >> 16) | (p3 & 0xFFFF0000u) };
            int woff = ((r * 128) + 32 * kt2 + 8 * g) ^ ((r & 7) << 4);
            *(uu2*)(Pw + woff) = dw;
        }
        // ---- Z += P.X^T kb=0 (wave-internal LDS is in-order) ----
        {
            int poff = ((r * 128) + g * 16) ^ ((r & 7) << 4);
            s8v pa = *(const s8v*)(Pw + poff);
            #pragma unroll
            for (int ot = 0; ot < 4; ++ot) {
                int goff = (((ot * 16 + r) * 128) + g * 16) ^ ((r & 7) << 4);
                s8v gf = *(const s8v*)(G_lds + goff);
                of[ot] = __builtin_amdgcn_mfma_f32_16x16x32_bf16(pa, gf, of[ot], 0, 0, 0);
            }
        }
        // ---- P keys 32..63 (kt2 = 2,3) ----
        #pragma unroll
        for (int kt2 = 2; kt2 < 4; ++kt2) {
            uint p0 = __float_as_uint(__builtin_exp2f(fmaf(sf[kt2][0], L2E, nm)));
            uint p1 = __float_as_uint(__builtin_exp2f(fmaf(sf[kt2][1], L2E, nm)));
            uint p2 = __float_as_uint(__builtin_exp2f(fmaf(sf[kt2][2], L2E, nm)));
            uint p3 = __float_as_uint(__builtin_exp2f(fmaf(sf[kt2][3], L2E, nm)));
            uu2 dw = { (p0 >> 16) | (p1 & 0xFFFF0000u),
                       (p2 >> 16) | (p3 & 0xFFFF0000u) };
            int woff = ((r * 128) + 32 * kt2 + 8 * g) ^ ((r & 7) << 4);
            *(uu2*)(Pw + woff) = dw;
        }
        // ---- Z += P.X^T kb=1 ----
        {
            int poff = ((r * 128) + 64 + g * 16) ^ ((r & 7) << 4);
            s8v pa = *(const s8v*)(Pw + poff);
            #pragma unroll
            for (int ot = 0; ot < 4; ++ot) {
                int goff = (((ot * 16 + r) * 128) + 64 + g * 16) ^ ((r & 7) << 4);
                s8v gf = *(const s8v*)(G_lds + goff);
                of[ot] = __builtin_amdgcn_mfma_f32_16x16x32_bf16(pa, gf, of[ot], 0, 0, 0);
            }
        }

        if (more) {
            __syncthreads();                  // all waves done reading K/X^T
            lds_write();
            __syncthreads();                  // next tile staged
        }
    }

    // epilogue: unnormalized Z (+ l in col 60); k_cout applies M and divides
    int qb = q0 + wv * 16 + 4 * g;
    ushort* Ob = O_bf + ((size_t)(s * BB + b) * DP) * NN;
    #pragma unroll
    for (int ot = 0; ot < 4; ++ot) {
        int o = ot * 16 + r;
        u4v v = {f2bf_bits(of[ot][0]), f2bf_bits(of[ot][1]),
                 f2bf_bits(of[ot][2]), f2bf_bits(of[ot][3])};
        *(u4v*)&Ob[(size_t)o * NN + qb] = v;                 // coalesced 32B per r-group
    }
}

// ---------- K4 (fused combine+out): r24 structure (block per 32 pixels, grid
// BB*128, phase-2 8 outputs/thread) with VECTORIZED phase 1: 16 pixel-pairs x
// 16 o-groups, u32 pair-loads (2 bf16/load; was 32 scalar bf16 loads/thread).
template <int NS>
__global__ __launch_bounds__(256) void k_cout(const ushort* __restrict__ O_bf,
                                              const float* __restrict__ Mc,
                                              const float* __restrict__ x,
                                              float* __restrict__ out) {
    __shared__ float ww[DD * DD];                      // 14.4 KB (= M)
    __shared__ float wb[DD];                           //          (= c)
    __shared__ float zlds[32][61];                     // 7.8 KB
    __shared__ float linv[32];

    int b  = blockIdx.x >> 7;                          // grid = BB*128
    int n0 = (blockIdx.x & 127) * 32;
    int tid = threadIdx.x;
    for (int i = tid; i < DD * DD; i += 256) ww[i] = Mc[i];
    if (tid < DD) wb[tid] = Mc[DD * DD + tid];

    // ---- phase 1 (vectorized): pixel pair pp = tid&15 (pixels 2pp, 2pp+1),
    //      o-group tid>>4 handles 4 o's; u32 loads = 2 pixels at once ----
    {
        int pp   = tid & 15;
        int ogrp = tid >> 4;                           // 0..15
        const ushort* Op = O_bf + (size_t)b * DP * NN + n0 + 2 * pp;
        #pragma unroll
        for (int i = 0; i < 4; ++i) {
            int o = ogrp * 4 + i;                      // 0..63
            if (o > DD) continue;                      // o<=60 processed
            float s0 = 0.f, s1 = 0.f;
            #pragma unroll
            for (int ss = 0; ss < NS; ++ss) {
                uint v = *(const uint*)&Op[(size_t)ss * BB * DP * NN + (size_t)o * NN];
                s0 += bf2f_lo(v);
                s1 += bf2f_hi(v);
            }
            if (o < DD) { zlds[2 * pp][o] = s0; zlds[2 * pp + 1][o] = s1; }
            else        { linv[2 * pp] = 1.0f / s0; linv[2 * pp + 1] = 1.0f / s1; }
        }
    }
    __syncthreads();

    // ---- phase 2: 8 outputs per thread (o = 8k+ogrp), M from LDS, z from LDS ----
    int pix  = tid & 31;
    int ogrp = tid >> 5;                               // 0..7
    int n = n0 + pix;
    float li = linv[pix];
    int oh = n >> 6, ow = n & 63;
    #pragma unroll
    for (int k = 0; k < 8; ++k) {
        int o = k * 8 + ogrp;
        if (o < DD) {
            float acc = 0.f;
            #pragma unroll
            for (int d = 0; d < DD; ++d)
                acc = fmaf(ww[o * DD + d], zlds[pix][d], acc);
            int c1 = o >> 2, r1 = (o >> 1) & 1, r2 = o & 1;
            size_t xi = ((size_t)(b * TC + c1) * HH + 2 * oh + r1) * HH + 2 * ow + r2;
            out[xi] = fmaf(acc, li, wb[o]) + x[xi];
        }
    }
}

extern "C" void kernel_launch(void* const* d_in, const int* in_sizes, int n_in,
                              void* d_out, int out_size, void* d_ws, size_t ws_size,
                              hipStream_t stream) {
    const float* x   = (const float*)d_in[0];
    const float* g_w = (const float*)d_in[1];
    const float* g_b = (const float*)d_in[2];
    const float* w_w = (const float*)d_in[3];
    const float* w_b = (const float*)d_in[4];
    float* out = (float*)d_out;

    char* ws = (char*)d_ws;
    ushort* xf2    = (ushort*)ws;                      // 2,097,152 B (B,64,N)
    ushort* xf_t   = (ushort*)(ws + 2097152);          // 2,097,152 B (B,N,64)
    float*  rnorm  = (float*)(ws + 4194304);           // 65,536 B
    uint*   mxbits = (uint*)(ws + 4259840);            // 256 B
    float*  Mc     = (float*)(ws + 4260096);           // 16,384 B  (3600 M + 60 c)
    ushort* O_bf   = (ushort*)(ws + 4276480);          // 8,388,608 B (NS=4) -> end 12,665,088
    const size_t SPLIT_NEED = 12665088;

    k_mw<<<16, 256, 0, stream>>>(g_w, g_b, w_w, w_b, Mc, mxbits);  // also zeroes mxbits
    k_prep<<<BB * NN / 32, 256, 0, stream>>>(x, xf2, xf_t, rnorm, mxbits);

    if (ws_size >= SPLIT_NEED) {
        k_attn<NSPLIT><<<NSPLIT * BB * (NN / QT), 256, 0, stream>>>(
            xf_t, xf2, rnorm, mxbits, O_bf);
        k_cout<NSPLIT><<<BB * 128, 256, 0, stream>>>(O_bf, Mc, x, out);
    } else {
        k_attn<1><<<BB * (NN / QT), 256, 0, stream>>>(
            xf_t, xf2, rnorm, mxbits, O_bf);
        k_cout<1><<<BB * 128, 256, 0, stream>>>(O_bf, Mc, x, out);
    }
}

// Round 30
// 65.555 us; speedup vs baseline: 1.3377x; 1.0029x over previous
//
#include <hip/hip_runtime.h>
#include <hip/hip_bf16.h>

// x: (B=4, T=5, C=3, H=128, W=128) fp32 ; R=2 ; D = 60 ; N = 4096
#define BB 4
#define TC 15
#define DD 60
#define NN 4096
#define HH 128
#define DP 64
#define KT 64
#define NWAVE 4
#define QT 64
#define NTILES 64
#define NSPLIT 4
#define L2E 1.4426950408889634f

typedef short s8v __attribute__((ext_vector_type(8)));   // 8 x bf16
typedef ushort u4v __attribute__((ext_vector_type(4)));
typedef uint  uu2 __attribute__((ext_vector_type(2)));
typedef float f4v __attribute__((ext_vector_type(4)));
typedef float f2v __attribute__((ext_vector_type(2)));

static __device__ __forceinline__ ushort f2bf_bits(float f) {
    __hip_bfloat16 h = __float2bfloat16(f);
    return *reinterpret_cast<ushort*>(&h);
}
static __device__ __forceinline__ float bf2f(ushort w) { return __uint_as_float((uint)w << 16); }
static __device__ __forceinline__ float bf2f_lo(uint u) { return __uint_as_float(u << 16); }
static __device__ __forceinline__ float bf2f_hi(uint u) { return __uint_as_float(u & 0xFFFF0000u); }

// ---------- K1 (fused): blocks 0..511 = d-parallel prep; blocks 512..527 = Mc.
// mxbits zeroed by hipMemsetAsync before this kernel (same-stream ordering).
// Mc: M = w_w.g_w (60x60) ; c = w_w.g_b + w_b  (out = (Z/l).M^T + c algebra).
__global__ __launch_bounds__(256) void k_prep(const float* __restrict__ x,
                                              ushort* __restrict__ xf2,
                                              ushort* __restrict__ xf_t,
                                              float* __restrict__ rnorm,
                                              uint* __restrict__ mxbits,
                                              const float* __restrict__ g_w,
                                              const float* __restrict__ g_b,
                                              const float* __restrict__ w_w,
                                              const float* __restrict__ w_b,
                                              float* __restrict__ Mc) {
    if (blockIdx.x >= 512) {                           // ---- Mc blocks ----
        int idx = (blockIdx.x - 512) * 256 + threadIdx.x;
        if (idx < DD * DD) {
            int p = idx / DD, d = idx % DD;
            float acc = 0.f;
            #pragma unroll
            for (int o = 0; o < DD; ++o)
                acc = fmaf(w_w[p * DD + o], g_w[o * DD + d], acc);
            Mc[idx] = acc;
        } else if (idx < DD * DD + DD) {
            int p = idx - DD * DD;
            float acc = w_b[p];
            #pragma unroll
            for (int o = 0; o < DD; ++o)
                acc = fmaf(w_w[p * DD + o], g_b[o], acc);
            Mc[idx] = acc;
        }
        return;
    }
    __shared__ float ssp[8][33];
    int tid = threadIdx.x;
    int pix = tid & 31, j = tid >> 5;                  // d-group j: d = 8j..8j+7
    int n = blockIdx.x * 32 + pix;                     // blocks never cross b (128/batch)
    int b = n >> 12, nn = n & (NN - 1);
    int oh = nn >> 6, ow = nn & 63;
    const float* xb = x + (size_t)b * TC * HH * HH;
    ushort* x2 = xf2 + (size_t)b * DP * NN + nn;
    ushort row[8];
    float ss = 0.f;
    const int nh = (j < 7) ? 4 : 2;                    // j=7: only c1=14 (d 56..59)
    #pragma unroll
    for (int h = 0; h < 4; ++h) {
        if (h < nh) {
            int c1 = 2 * j + (h >> 1), r1 = h & 1;
            f2v v = *(const f2v*)&xb[(c1 * HH + oh * 2 + r1) * HH + ow * 2];
            ushort w0 = f2bf_bits(v[0]), w1 = f2bf_bits(v[1]);
            row[2 * h] = w0; row[2 * h + 1] = w1;
            float f0 = bf2f(w0), f1 = bf2f(w1);
            ss = fmaf(f0, f0, ss);
            ss = fmaf(f1, f1, ss);
            int d0 = 8 * j + 2 * h;
            x2[(size_t)d0 * NN] = w0;
            x2[(size_t)(d0 + 1) * NN] = w1;
        } else {
            row[2 * h] = 0; row[2 * h + 1] = 0;        // xf_t padding d 60..63 = 0
        }
    }
    if (j == 7) {                                      // xf2 special rows
        x2[(size_t)60 * NN] = (ushort)0x3F80;          // ones row -> l accumulator
        x2[(size_t)61 * NN] = 0;
        x2[(size_t)62 * NN] = 0;
        x2[(size_t)63 * NN] = 0;
    }
    *(s8v*)&xf_t[(size_t)n * DP + j * 8] = *(const s8v*)row;

    ssp[j][pix] = ss;
    __syncthreads();
    if (tid < 32) {
        float tot = ssp[0][tid] + ssp[1][tid] + ssp[2][tid] + ssp[3][tid]
                  + ssp[4][tid] + ssp[5][tid] + ssp[6][tid] + ssp[7][tid];
        float norm = sqrtf(tot) * 1.0002f;             // safety margin: m bounds row max
        rnorm[blockIdx.x * 32 + tid] = norm;
        float mv = norm;
        #pragma unroll
        for (int off = 1; off < 32; off <<= 1) mv = fmaxf(mv, __shfl_xor(mv, off));
        if (tid == 0) atomicMax(&mxbits[b], __float_as_uint(mv));
    }
}

// ---------- K3: flash attention, split-K=4, SWAPPED-OPERAND QK^T (r28 proven).
// S^T = mfma(K_frag, Q_frag): lane holds S[query=r][key=16*kt2+4g+reg]; nm scalar;
// 4 packed b64 P-writes per tile (bank cost is data-volume-intrinsic).
// Z = P.X^T with xf2 row 60 = 1 -> l. k_cout applies M and divides. UNCHANGED.
template <int NS>
__global__ __launch_bounds__(256, 2) void k_attn(const ushort* __restrict__ xf_t,
                                                 const ushort* __restrict__ x2_bf, // (B,64,N)
                                                 const float* __restrict__ rnorm,
                                                 const uint* __restrict__ mxbits,
                                                 ushort* __restrict__ O_bf) {  // (s,b,64,N) bf16
    __shared__ char K_lds[KT * 128];                   // 8 KB
    __shared__ char G_lds[DP * 128];                   // 8 KB (X^T tile)
    __shared__ char P_lds[NWAVE][16 * 128];            // 8 KB

    int p = blockIdx.x;
    int s, b, q0;
    if (NS == NSPLIT) {
        // XCD-aware: xcd = p&7; each XCD pair-half owns one batch (~1MB = L2-hot)
        int xcd = p & 7, slot = p >> 3;                // slot in [0,128)
        b = xcd >> 1;
        s = (xcd & 1) * 2 + (slot >> 6);               // NS=4: 2 splits per xcd-half
        q0 = (slot & 63) * QT;
    } else {
        s = 0;
        b = p >> 6;
        q0 = (p & 63) * QT;
    }
    int tid = threadIdx.x;
    int lane = tid & 63, wv = tid >> 6;
    int r = lane & 15, g = lane >> 4;

    const ushort* Xt = xf_t + (size_t)b * NN * DP;
    const ushort* Gb = x2_bf + (size_t)b * DP * NN;

    int qrow = q0 + wv * 16 + r;
    s8v qa[2];
    qa[0] = *(const s8v*)&Xt[(size_t)qrow * DP + g * 8];
    qa[1] = *(const s8v*)&Xt[(size_t)qrow * DP + 32 + g * 8];

    // fixed softmax shift: query is lane-fixed (= r) -> ONE scalar
    float mx = __uint_as_float(mxbits[b]);
    float nm = -rnorm[b * NN + qrow] * mx * L2E;

    f4v of[4];
    #pragma unroll
    for (int i = 0; i < 4; ++i) of[i] = (f4v){0.f, 0.f, 0.f, 0.f};

    // staging: 256 threads x two 16B units per buffer; row = e>>3, j = e&7
    const int e0 = tid, e1 = 256 + tid;
    const int kr0 = e0 >> 3, kj0 = e0 & 7;             // rows 0..31
    const int kr1 = e1 >> 3, kj1 = e1 & 7;             // rows 32..63
    const int kw0 = (kr0 * 128 + kj0 * 16) ^ ((kr0 & 7) << 4);
    const int kw1 = (kr1 * 128 + kj1 * 16) ^ ((kr1 & 7) << 4);
    s8v kp0, kp1, gp0, gp1;

    auto stage_regs = [&](int t) {
        int n0 = t * KT;
        kp0 = *(const s8v*)&Xt[(size_t)(n0 + kr0) * DP + kj0 * 8];
        kp1 = *(const s8v*)&Xt[(size_t)(n0 + kr1) * DP + kj1 * 8];
        gp0 = *(const s8v*)&Gb[(size_t)kr0 * NN + n0 + kj0 * 8];   // branch-free: 64 rows
        gp1 = *(const s8v*)&Gb[(size_t)kr1 * NN + n0 + kj1 * 8];
    };
    auto lds_write = [&]() {
        *(s8v*)(K_lds + kw0) = kp0;
        *(s8v*)(K_lds + kw1) = kp1;
        *(s8v*)(G_lds + kw0) = gp0;
        *(s8v*)(G_lds + kw1) = gp1;
    };

    const int t0 = s * (NTILES / NS);
    const int tend = t0 + NTILES / NS;
    char* Pw = P_lds[wv];

    stage_regs(t0);
    lds_write();
    __syncthreads();

    #pragma unroll 1
    for (int t = t0; t < tend; ++t) {
        bool more = (t + 1 < tend);
        if (more) stage_regs(t + 1);          // global loads in flight during compute

        // ---- S^T = K.Q^T (swapped operands; same LDS reads) ----
        f4v sf[4];
        #pragma unroll
        for (int i = 0; i < 4; ++i) sf[i] = (f4v){0.f, 0.f, 0.f, 0.f};
        #pragma unroll
        for (int kt2 = 0; kt2 < 4; ++kt2)
            #pragma unroll
            for (int kb = 0; kb < 2; ++kb) {
                int off = (((kt2 * 16 + r) * 128) + kb * 64 + g * 16) ^ ((r & 7) << 4);
                s8v bf = *(const s8v*)(K_lds + off);
                sf[kt2] = __builtin_amdgcn_mfma_f32_16x16x32_bf16(bf, qa[kb], sf[kt2], 0, 0, 0);
            }

        // ---- P keys 0..31 (kt2 = 0,1): 4 exp2 -> 2 packed dwords -> 1 b64 write ----
        #pragma unroll
        for (int kt2 = 0; kt2 < 2; ++kt2) {
            uint p0 = __float_as_uint(__builtin_exp2f(fmaf(sf[kt2][0], L2E, nm)));
            uint p1 = __float_as_uint(__builtin_exp2f(fmaf(sf[kt2][1], L2E, nm)));
            uint p2 = __float_as_uint(__builtin_exp2f(fmaf(sf[kt2][2], L2E, nm)));
            uint p3 = __float_as_uint(__builtin_exp2f(fmaf(sf[kt2][3], L2E, nm)));
            uu2 dw = { (p0 >> 16) | (p1 & 0xFFFF0000u),
                       (p2 >> 16) | (p3 & 0xFFFF0000u) };
            int woff = ((r * 128) + 32 * kt2 + 8 * g) ^ ((r & 7) << 4);
            *(uu2*)(Pw + woff) = dw;
        }
        // ---- Z += P.X^T kb=0 (wave-internal LDS is in-order) ----
        {
            int poff = ((r * 128) + g * 16) ^ ((r & 7) << 4);
            s8v pa = *(const s8v*)(Pw + poff);
            #pragma unroll
            for (int ot = 0; ot < 4; ++ot) {
                int goff = (((ot * 16 + r) * 128) + g * 16) ^ ((r & 7) << 4);
                s8v gf = *(const s8v*)(G_lds + goff);
                of[ot] = __builtin_amdgcn_mfma_f32_16x16x32_bf16(pa, gf, of[ot], 0, 0, 0);
            }
        }
        // ---- P keys 32..63 (kt2 = 2,3) ----
        #pragma unroll
        for (int kt2 = 2; kt2 < 4; ++kt2) {
            uint p0 = __float_as_uint(__builtin_exp2f(fmaf(sf[kt2][0], L2E, nm)));
            uint p1 = __float_as_uint(__builtin_exp2f(fmaf(sf[kt2][1], L2E, nm)));
            uint p2 = __float_as_uint(__builtin_exp2f(fmaf(sf[kt2][2], L2E, nm)));
            uint p3 = __float_as_uint(__builtin_exp2f(fmaf(sf[kt2][3], L2E, nm)));
            uu2 dw = { (p0 >> 16) | (p1 & 0xFFFF0000u),
                       (p2 >> 16) | (p3 & 0xFFFF0000u) };
            int woff = ((r * 128) + 32 * kt2 + 8 * g) ^ ((r & 7) << 4);
            *(uu2*)(Pw + woff) = dw;
        }
        // ---- Z += P.X^T kb=1 ----
        {
            int poff = ((r * 128) + 64 + g * 16) ^ ((r & 7) << 4);
            s8v pa = *(const s8v*)(Pw + poff);
            #pragma unroll
            for (int ot = 0; ot < 4; ++ot) {
                int goff = (((ot * 16 + r) * 128) + 64 + g * 16) ^ ((r & 7) << 4);
                s8v gf = *(const s8v*)(G_lds + goff);
                of[ot] = __builtin_amdgcn_mfma_f32_16x16x32_bf16(pa, gf, of[ot], 0, 0, 0);
            }
        }

        if (more) {
            __syncthreads();                  // all waves done reading K/X^T
            lds_write();
            __syncthreads();                  // next tile staged
        }
    }

    // epilogue: unnormalized Z (+ l in col 60); k_cout applies M and divides
    int qb = q0 + wv * 16 + 4 * g;
    ushort* Ob = O_bf + ((size_t)(s * BB + b) * DP) * NN;
    #pragma unroll
    for (int ot = 0; ot < 4; ++ot) {
        int o = ot * 16 + r;
        u4v v = {f2bf_bits(of[ot][0]), f2bf_bits(of[ot][1]),
                 f2bf_bits(of[ot][2]), f2bf_bits(of[ot][3])};
        *(u4v*)&Ob[(size_t)o * NN + qb] = v;                 // coalesced 32B per r-group
    }
}

// ---------- K4 (fused combine+out): r29 structure with o-PAIR phase 2:
// each thread does 4 even/odd o-pairs -> f2v x-loads and out-stores (r2 = 0/1
// at same (c1,r1) => adjacent xi). Phase 1 u32 pixel-pair loads unchanged.
template <int NS>
__global__ __launch_bounds__(256) void k_cout(const ushort* __restrict__ O_bf,
                                              const float* __restrict__ Mc,
                                              const float* __restrict__ x,
                                              float* __restrict__ out) {
    __shared__ float ww[DD * DD];                      // 14.4 KB (= M)
    __shared__ float wb[DD];                           //          (= c)
    __shared__ float zlds[32][61];                     // 7.8 KB
    __shared__ float linv[32];

    int b  = blockIdx.x >> 7;                          // grid = BB*128
    int n0 = (blockIdx.x & 127) * 32;
    int tid = threadIdx.x;
    for (int i = tid; i < DD * DD; i += 256) ww[i] = Mc[i];
    if (tid < DD) wb[tid] = Mc[DD * DD + tid];

    // ---- phase 1 (vectorized): pixel pair pp = tid&15 (pixels 2pp, 2pp+1),
    //      o-group tid>>4 handles 4 o's; u32 loads = 2 pixels at once ----
    {
        int pp   = tid & 15;
        int ogrp = tid >> 4;                           // 0..15
        const ushort* Op = O_bf + (size_t)b * DP * NN + n0 + 2 * pp;
        #pragma unroll
        for (int i = 0; i < 4; ++i) {
            int o = ogrp * 4 + i;                      // 0..63
            if (o > DD) continue;                      // o<=60 processed
            float s0 = 0.f, s1 = 0.f;
            #pragma unroll
            for (int ss = 0; ss < NS; ++ss) {
                uint v = *(const uint*)&Op[(size_t)ss * BB * DP * NN + (size_t)o * NN];
                s0 += bf2f_lo(v);
                s1 += bf2f_hi(v);
            }
            if (o < DD) { zlds[2 * pp][o] = s0; zlds[2 * pp + 1][o] = s1; }
            else        { linv[2 * pp] = 1.0f / s0; linv[2 * pp + 1] = 1.0f / s1; }
        }
    }
    __syncthreads();

    // ---- phase 2: 4 o-pairs per thread (o = 2*(8k+ogrp)), f2v load/store ----
    int pix  = tid & 31;
    int ogrp = tid >> 5;                               // 0..7
    int n = n0 + pix;
    float li = linv[pix];
    int oh = n >> 6, ow = n & 63;
    #pragma unroll
    for (int k = 0; k < 4; ++k) {
        int o = 2 * (8 * k + ogrp);                    // even o: 0..62
        if (o < DD) {                                  // covers pairs (0,1)..(58,59)
            float a0 = 0.f, a1 = 0.f;
            #pragma unroll
            for (int d = 0; d < DD; ++d) {
                float z = zlds[pix][d];
                a0 = fmaf(ww[o * DD + d], z, a0);
                a1 = fmaf(ww[(o + 1) * DD + d], z, a1);
            }
            int c1 = o >> 2, r1 = (o >> 1) & 1;        // r2 = 0 then 1 (adjacent xi)
            size_t xi = ((size_t)(b * TC + c1) * HH + 2 * oh + r1) * HH + 2 * ow;
            f2v xv = *(const f2v*)&x[xi];
            f2v res = {fmaf(a0, li, wb[o]) + xv[0], fmaf(a1, li, wb[o + 1]) + xv[1]};
            *(f2v*)&out[xi] = res;
        }
    }
}

extern "C" void kernel_launch(void* const* d_in, const int* in_sizes, int n_in,
                              void* d_out, int out_size, void* d_ws, size_t ws_size,
                              hipStream_t stream) {
    const float* x   = (const float*)d_in[0];
    const float* g_w = (const float*)d_in[1];
    const float* g_b = (const float*)d_in[2];
    const float* w_w = (const float*)d_in[3];
    const float* w_b = (const float*)d_in[4];
    float* out = (float*)d_out;

    char* ws = (char*)d_ws;
    ushort* xf2    = (ushort*)ws;                      // 2,097,152 B (B,64,N)
    ushort* xf_t   = (ushort*)(ws + 2097152);          // 2,097,152 B (B,N,64)
    float*  rnorm  = (float*)(ws + 4194304);           // 65,536 B
    uint*   mxbits = (uint*)(ws + 4259840);            // 256 B
    float*  Mc     = (float*)(ws + 4260096);           // 16,384 B  (3600 M + 60 c)
    ushort* O_bf   = (ushort*)(ws + 4276480);          // 8,388,608 B (NS=4) -> end 12,665,088
    const size_t SPLIT_NEED = 12665088;

    hipMemsetAsync(mxbits, 0, BB * sizeof(uint), stream);
    k_prep<<<528, 256, 0, stream>>>(x, xf2, xf_t, rnorm, mxbits,
                                    g_w, g_b, w_w, w_b, Mc);   // blocks 512+ do Mc

    if (ws_size >= SPLIT_NEED) {
        k_attn<NSPLIT><<<NSPLIT * BB * (NN / QT), 256, 0, stream>>>(
            xf_t, xf2, rnorm, mxbits, O_bf);
        k_cout<NSPLIT><<<BB * 128, 256, 0, stream>>>(O_bf, Mc, x, out);
    } else {
        k_attn<1><<<BB * (NN / QT), 256, 0, stream>>>(
            xf_t, xf2, rnorm, mxbits, O_bf);
        k_cout<1><<<BB * 128, 256, 0, stream>>>(O_bf, Mc, x, out);
    }
}

// Round 31
// 64.925 us; speedup vs baseline: 1.3507x; 1.0097x over previous
//
#include <hip/hip_runtime.h>
#include <hip/hip_bf16.h>

// x: (B=4, T=5, C=3, H=128, W=128) fp32 ; R=2 ; D = 60 ; N = 4096
#define BB 4
#define TC 15
#define DD 60
#define NN 4096
#define HH 128
#define DP 64
#define KT 64
#define NWAVE 4
#define QT 64
#define NTILES 64
#define NSPLIT 4
#define L2E 1.4426950408889634f

typedef short s8v __attribute__((ext_vector_type(8)));   // 8 x bf16
typedef ushort u4v __attribute__((ext_vector_type(4)));
typedef uint  uu2 __attribute__((ext_vector_type(2)));
typedef float f4v __attribute__((ext_vector_type(4)));
typedef float f2v __attribute__((ext_vector_type(2)));

static __device__ __forceinline__ ushort f2bf_bits(float f) {
    __hip_bfloat16 h = __float2bfloat16(f);
    return *reinterpret_cast<ushort*>(&h);
}
static __device__ __forceinline__ float bf2f(ushort w) { return __uint_as_float((uint)w << 16); }
static __device__ __forceinline__ float bf2f_lo(uint u) { return __uint_as_float(u << 16); }
static __device__ __forceinline__ float bf2f_hi(uint u) { return __uint_as_float(u & 0xFFFF0000u); }

// ---------- K1 (fused): blocks 0..511 = d-parallel prep; blocks 512..527 = Mc.
// mxbits zeroed by hipMemsetAsync before this kernel (same-stream ordering).
// Mc: M = w_w.g_w (60x60) ; c = w_w.g_b + w_b  (out = (Z/l).M^T + c algebra).
__global__ __launch_bounds__(256) void k_prep(const float* __restrict__ x,
                                              ushort* __restrict__ xf2,
                                              ushort* __restrict__ xf_t,
                                              float* __restrict__ rnorm,
                                              uint* __restrict__ mxbits,
                                              const float* __restrict__ g_w,
                                              const float* __restrict__ g_b,
                                              const float* __restrict__ w_w,
                                              const float* __restrict__ w_b,
                                              float* __restrict__ Mc) {
    if (blockIdx.x >= 512) {                           // ---- Mc blocks ----
        int idx = (blockIdx.x - 512) * 256 + threadIdx.x;
        if (idx < DD * DD) {
            int p = idx / DD, d = idx % DD;
            float acc = 0.f;
            #pragma unroll
            for (int o = 0; o < DD; ++o)
                acc = fmaf(w_w[p * DD + o], g_w[o * DD + d], acc);
            Mc[idx] = acc;
        } else if (idx < DD * DD + DD) {
            int p = idx - DD * DD;
            float acc = w_b[p];
            #pragma unroll
            for (int o = 0; o < DD; ++o)
                acc = fmaf(w_w[p * DD + o], g_b[o], acc);
            Mc[idx] = acc;
        }
        return;
    }
    __shared__ float ssp[8][33];
    int tid = threadIdx.x;
    int pix = tid & 31, j = tid >> 5;                  // d-group j: d = 8j..8j+7
    int n = blockIdx.x * 32 + pix;                     // blocks never cross b (128/batch)
    int b = n >> 12, nn = n & (NN - 1);
    int oh = nn >> 6, ow = nn & 63;
    const float* xb = x + (size_t)b * TC * HH * HH;
    ushort* x2 = xf2 + (size_t)b * DP * NN + nn;
    ushort row[8];
    float ss = 0.f;
    const int nh = (j < 7) ? 4 : 2;                    // j=7: only c1=14 (d 56..59)
    #pragma unroll
    for (int h = 0; h < 4; ++h) {
        if (h < nh) {
            int c1 = 2 * j + (h >> 1), r1 = h & 1;
            f2v v = *(const f2v*)&xb[(c1 * HH + oh * 2 + r1) * HH + ow * 2];
            ushort w0 = f2bf_bits(v[0]), w1 = f2bf_bits(v[1]);
            row[2 * h] = w0; row[2 * h + 1] = w1;
            float f0 = bf2f(w0), f1 = bf2f(w1);
            ss = fmaf(f0, f0, ss);
            ss = fmaf(f1, f1, ss);
            int d0 = 8 * j + 2 * h;
            x2[(size_t)d0 * NN] = w0;
            x2[(size_t)(d0 + 1) * NN] = w1;
        } else {
            row[2 * h] = 0; row[2 * h + 1] = 0;        // xf_t padding d 60..63 = 0
        }
    }
    if (j == 7) {                                      // xf2 special rows
        x2[(size_t)60 * NN] = (ushort)0x3F80;          // ones row -> l accumulator
        x2[(size_t)61 * NN] = 0;
        x2[(size_t)62 * NN] = 0;
        x2[(size_t)63 * NN] = 0;
    }
    *(s8v*)&xf_t[(size_t)n * DP + j * 8] = *(const s8v*)row;

    ssp[j][pix] = ss;
    __syncthreads();
    if (tid < 32) {
        float tot = ssp[0][tid] + ssp[1][tid] + ssp[2][tid] + ssp[3][tid]
                  + ssp[4][tid] + ssp[5][tid] + ssp[6][tid] + ssp[7][tid];
        float norm = sqrtf(tot) * 1.0002f;             // safety margin: m bounds row max
        rnorm[blockIdx.x * 32 + tid] = norm;
        float mv = norm;
        #pragma unroll
        for (int off = 1; off < 32; off <<= 1) mv = fmaxf(mv, __shfl_xor(mv, off));
        if (tid == 0) atomicMax(&mxbits[b], __float_as_uint(mv));
    }
}

// ---------- K3: flash attention, split-K=4, SWAPPED-OPERAND QK^T.
// S^T = mfma(K_frag, Q_frag): lane holds S[query=r][key=16*kt2+4g+reg]; nm scalar.
// MERGED phases (r30): ONE P-phase (16 exp2 + 4 packed b64 writes), ONE PV-phase
// (8 MFMAs) — the kb0 pa-read's lgkmcnt overlaps the kt2=2,3 exp/write stream
// instead of stalling right after its producing writes. Data flow unchanged.
// Z = P.X^T with xf2 row 60 = 1 -> l. k_cout applies M and divides.
template <int NS>
__global__ __launch_bounds__(256, 2) void k_attn(const ushort* __restrict__ xf_t,
                                                 const ushort* __restrict__ x2_bf, // (B,64,N)
                                                 const float* __restrict__ rnorm,
                                                 const uint* __restrict__ mxbits,
                                                 ushort* __restrict__ O_bf) {  // (s,b,64,N) bf16
    __shared__ char K_lds[KT * 128];                   // 8 KB
    __shared__ char G_lds[DP * 128];                   // 8 KB (X^T tile)
    __shared__ char P_lds[NWAVE][16 * 128];            // 8 KB

    int p = blockIdx.x;
    int s, b, q0;
    if (NS == NSPLIT) {
        // XCD-aware: xcd = p&7; each XCD pair-half owns one batch (~1MB = L2-hot)
        int xcd = p & 7, slot = p >> 3;                // slot in [0,128)
        b = xcd >> 1;
        s = (xcd & 1) * 2 + (slot >> 6);               // NS=4: 2 splits per xcd-half
        q0 = (slot & 63) * QT;
    } else {
        s = 0;
        b = p >> 6;
        q0 = (p & 63) * QT;
    }
    int tid = threadIdx.x;
    int lane = tid & 63, wv = tid >> 6;
    int r = lane & 15, g = lane >> 4;

    const ushort* Xt = xf_t + (size_t)b * NN * DP;
    const ushort* Gb = x2_bf + (size_t)b * DP * NN;

    int qrow = q0 + wv * 16 + r;
    s8v qa[2];
    qa[0] = *(const s8v*)&Xt[(size_t)qrow * DP + g * 8];
    qa[1] = *(const s8v*)&Xt[(size_t)qrow * DP + 32 + g * 8];

    // fixed softmax shift: query is lane-fixed (= r) -> ONE scalar
    float mx = __uint_as_float(mxbits[b]);
    float nm = -rnorm[b * NN + qrow] * mx * L2E;

    f4v of[4];
    #pragma unroll
    for (int i = 0; i < 4; ++i) of[i] = (f4v){0.f, 0.f, 0.f, 0.f};

    // staging: 256 threads x two 16B units per buffer; row = e>>3, j = e&7
    const int e0 = tid, e1 = 256 + tid;
    const int kr0 = e0 >> 3, kj0 = e0 & 7;             // rows 0..31
    const int kr1 = e1 >> 3, kj1 = e1 & 7;             // rows 32..63
    const int kw0 = (kr0 * 128 + kj0 * 16) ^ ((kr0 & 7) << 4);
    const int kw1 = (kr1 * 128 + kj1 * 16) ^ ((kr1 & 7) << 4);
    s8v kp0, kp1, gp0, gp1;

    auto stage_regs = [&](int t) {
        int n0 = t * KT;
        kp0 = *(const s8v*)&Xt[(size_t)(n0 + kr0) * DP + kj0 * 8];
        kp1 = *(const s8v*)&Xt[(size_t)(n0 + kr1) * DP + kj1 * 8];
        gp0 = *(const s8v*)&Gb[(size_t)kr0 * NN + n0 + kj0 * 8];   // branch-free: 64 rows
        gp1 = *(const s8v*)&Gb[(size_t)kr1 * NN + n0 + kj1 * 8];
    };
    auto lds_write = [&]() {
        *(s8v*)(K_lds + kw0) = kp0;
        *(s8v*)(K_lds + kw1) = kp1;
        *(s8v*)(G_lds + kw0) = gp0;
        *(s8v*)(G_lds + kw1) = gp1;
    };

    const int t0 = s * (NTILES / NS);
    const int tend = t0 + NTILES / NS;
    char* Pw = P_lds[wv];

    stage_regs(t0);
    lds_write();
    __syncthreads();

    #pragma unroll 1
    for (int t = t0; t < tend; ++t) {
        bool more = (t + 1 < tend);
        if (more) stage_regs(t + 1);          // global loads in flight during compute

        // ---- S^T = K.Q^T (swapped operands; same LDS reads) ----
        f4v sf[4];
        #pragma unroll
        for (int i = 0; i < 4; ++i) sf[i] = (f4v){0.f, 0.f, 0.f, 0.f};
        #pragma unroll
        for (int kt2 = 0; kt2 < 4; ++kt2)
            #pragma unroll
            for (int kb = 0; kb < 2; ++kb) {
                int off = (((kt2 * 16 + r) * 128) + kb * 64 + g * 16) ^ ((r & 7) << 4);
                s8v bf = *(const s8v*)(K_lds + off);
                sf[kt2] = __builtin_amdgcn_mfma_f32_16x16x32_bf16(bf, qa[kb], sf[kt2], 0, 0, 0);
            }

        // ---- P (all 64 keys): 16 exp2 -> 4 packed b64 writes ----
        #pragma unroll
        for (int kt2 = 0; kt2 < 4; ++kt2) {
            uint p0 = __float_as_uint(__builtin_exp2f(fmaf(sf[kt2][0], L2E, nm)));
            uint p1 = __float_as_uint(__builtin_exp2f(fmaf(sf[kt2][1], L2E, nm)));
            uint p2 = __float_as_uint(__builtin_exp2f(fmaf(sf[kt2][2], L2E, nm)));
            uint p3 = __float_as_uint(__builtin_exp2f(fmaf(sf[kt2][3], L2E, nm)));
            uu2 dw = { (p0 >> 16) | (p1 & 0xFFFF0000u),
                       (p2 >> 16) | (p3 & 0xFFFF0000u) };
            int woff = ((r * 128) + 32 * kt2 + 8 * g) ^ ((r & 7) << 4);
            *(uu2*)(Pw + woff) = dw;
        }
        // ---- Z += P.X^T (both kb halves; wave-internal LDS is in-order) ----
        #pragma unroll
        for (int kb = 0; kb < 2; ++kb) {
            int poff = ((r * 128) + kb * 64 + g * 16) ^ ((r & 7) << 4);
            s8v pa = *(const s8v*)(Pw + poff);
            #pragma unroll
            for (int ot = 0; ot < 4; ++ot) {
                int goff = (((ot * 16 + r) * 128) + kb * 64 + g * 16) ^ ((r & 7) << 4);
                s8v gf = *(const s8v*)(G_lds + goff);
                of[ot] = __builtin_amdgcn_mfma_f32_16x16x32_bf16(pa, gf, of[ot], 0, 0, 0);
            }
        }

        if (more) {
            __syncthreads();                  // all waves done reading K/X^T
            lds_write();
            __syncthreads();                  // next tile staged
        }
    }

    // epilogue: unnormalized Z (+ l in col 60); k_cout applies M and divides
    int qb = q0 + wv * 16 + 4 * g;
    ushort* Ob = O_bf + ((size_t)(s * BB + b) * DP) * NN;
    #pragma unroll
    for (int ot = 0; ot < 4; ++ot) {
        int o = ot * 16 + r;
        u4v v = {f2bf_bits(of[ot][0]), f2bf_bits(of[ot][1]),
                 f2bf_bits(of[ot][2]), f2bf_bits(of[ot][3])};
        *(u4v*)&Ob[(size_t)o * NN + qb] = v;                 // coalesced 32B per r-group
    }
}

// ---------- K4 (fused combine+out): phase 1 u32 pixel-pair loads; phase 2
// o-pair f2v loads/stores. Block per 32 pixels, grid BB*128.
template <int NS>
__global__ __launch_bounds__(256) void k_cout(const ushort* __restrict__ O_bf,
                                              const float* __restrict__ Mc,
                                              const float* __restrict__ x,
                                              float* __restrict__ out) {
    __shared__ float ww[DD * DD];                      // 14.4 KB (= M)
    __shared__ float wb[DD];                           //          (= c)
    __shared__ float zlds[32][61];                     // 7.8 KB
    __shared__ float linv[32];

    int b  = blockIdx.x >> 7;                          // grid = BB*128
    int n0 = (blockIdx.x & 127) * 32;
    int tid = threadIdx.x;
    for (int i = tid; i < DD * DD; i += 256) ww[i] = Mc[i];
    if (tid < DD) wb[tid] = Mc[DD * DD + tid];

    // ---- phase 1 (vectorized): pixel pair pp = tid&15 (pixels 2pp, 2pp+1),
    //      o-group tid>>4 handles 4 o's; u32 loads = 2 pixels at once ----
    {
        int pp   = tid & 15;
        int ogrp = tid >> 4;                           // 0..15
        const ushort* Op = O_bf + (size_t)b * DP * NN + n0 + 2 * pp;
        #pragma unroll
        for (int i = 0; i < 4; ++i) {
            int o = ogrp * 4 + i;                      // 0..63
            if (o > DD) continue;                      // o<=60 processed
            float s0 = 0.f, s1 = 0.f;
            #pragma unroll
            for (int ss = 0; ss < NS; ++ss) {
                uint v = *(const uint*)&Op[(size_t)ss * BB * DP * NN + (size_t)o * NN];
                s0 += bf2f_lo(v);
                s1 += bf2f_hi(v);
            }
            if (o < DD) { zlds[2 * pp][o] = s0; zlds[2 * pp + 1][o] = s1; }
            else        { linv[2 * pp] = 1.0f / s0; linv[2 * pp + 1] = 1.0f / s1; }
        }
    }
    __syncthreads();

    // ---- phase 2: 4 o-pairs per thread (o = 2*(8k+ogrp)), f2v load/store ----
    int pix  = tid & 31;
    int ogrp = tid >> 5;                               // 0..7
    int n = n0 + pix;
    float li = linv[pix];
    int oh = n >> 6, ow = n & 63;
    #pragma unroll
    for (int k = 0; k < 4; ++k) {
        int o = 2 * (8 * k + ogrp);                    // even o: 0..62
        if (o < DD) {                                  // covers pairs (0,1)..(58,59)
            float a0 = 0.f, a1 = 0.f;
            #pragma unroll
            for (int d = 0; d < DD; ++d) {
                float z = zlds[pix][d];
                a0 = fmaf(ww[o * DD + d], z, a0);
                a1 = fmaf(ww[(o + 1) * DD + d], z, a1);
            }
            int c1 = o >> 2, r1 = (o >> 1) & 1;        // r2 = 0 then 1 (adjacent xi)
            size_t xi = ((size_t)(b * TC + c1) * HH + 2 * oh + r1) * HH + 2 * ow;
            f2v xv = *(const f2v*)&x[xi];
            f2v res = {fmaf(a0, li, wb[o]) + xv[0], fmaf(a1, li, wb[o + 1]) + xv[1]};
            *(f2v*)&out[xi] = res;
        }
    }
}

extern "C" void kernel_launch(void* const* d_in, const int* in_sizes, int n_in,
                              void* d_out, int out_size, void* d_ws, size_t ws_size,
                              hipStream_t stream) {
    const float* x   = (const float*)d_in[0];
    const float* g_w = (const float*)d_in[1];
    const float* g_b = (const float*)d_in[2];
    const float* w_w = (const float*)d_in[3];
    const float* w_b = (const float*)d_in[4];
    float* out = (float*)d_out;

    char* ws = (char*)d_ws;
    ushort* xf2    = (ushort*)ws;                      // 2,097,152 B (B,64,N)
    ushort* xf_t   = (ushort*)(ws + 2097152);          // 2,097,152 B (B,N,64)
    float*  rnorm  = (float*)(ws + 4194304);           // 65,536 B
    uint*   mxbits = (uint*)(ws + 4259840);            // 256 B
    float*  Mc     = (float*)(ws + 4260096);           // 16,384 B  (3600 M + 60 c)
    ushort* O_bf   = (ushort*)(ws + 4276480);          // 8,388,608 B (NS=4) -> end 12,665,088
    const size_t SPLIT_NEED = 12665088;

    hipMemsetAsync(mxbits, 0, BB * sizeof(uint), stream);
    k_prep<<<528, 256, 0, stream>>>(x, xf2, xf_t, rnorm, mxbits,
                                    g_w, g_b, w_w, w_b, Mc);   // blocks 512+ do Mc

    if (ws_size >= SPLIT_NEED) {
        k_attn<NSPLIT><<<NSPLIT * BB * (NN / QT), 256, 0, stream>>>(
            xf_t, xf2, rnorm, mxbits, O_bf);
        k_cout<NSPLIT><<<BB * 128, 256, 0, stream>>>(O_bf, Mc, x, out);
    } else {
        k_attn<1><<<BB * (NN / QT), 256, 0, stream>>>(
            xf_t, xf2, rnorm, mxbits, O_bf);
        k_cout<1><<<BB * 128, 256, 0, stream>>>(O_bf, Mc, x, out);
    }
}

// Round 33
// 64.829 us; speedup vs baseline: 1.3527x; 1.0015x over previous
//
#include <hip/hip_runtime.h>
#include <hip/hip_bf16.h>

// x: (B=4, T=5, C=3, H=128, W=128) fp32 ; R=2 ; D = 60 ; N = 4096
#define BB 4
#define TC 15
#define DD 60
#define NN 4096
#define HH 128
#define DP 64
#define KT 64
#define NWAVE 4
#define QT 64
#define NTILES 64
#define NSPLIT 4
#define L2E 1.4426950408889634f

typedef short s8v __attribute__((ext_vector_type(8)));   // 8 x bf16
typedef ushort u4v __attribute__((ext_vector_type(4)));
typedef uint  uu2 __attribute__((ext_vector_type(2)));
typedef float f4v __attribute__((ext_vector_type(4)));
typedef float f2v __attribute__((ext_vector_type(2)));

static __device__ __forceinline__ ushort f2bf_bits(float f) {
    __hip_bfloat16 h = __float2bfloat16(f);
    return *reinterpret_cast<ushort*>(&h);
}
static __device__ __forceinline__ float bf2f(ushort w) { return __uint_as_float((uint)w << 16); }
static __device__ __forceinline__ float bf2f_lo(uint u) { return __uint_as_float(u << 16); }
static __device__ __forceinline__ float bf2f_hi(uint u) { return __uint_as_float(u & 0xFFFF0000u); }

// ---------- K1 (fused): blocks 0..511 = d-parallel prep; blocks 512..527 = Mc.
// mxbits zeroed by hipMemsetAsync before this kernel (same-stream ordering).
// Mc: M = w_w.g_w (60x60) ; c = w_w.g_b + w_b  (out = (Z/l).M^T + c algebra).
__global__ __launch_bounds__(256) void k_prep(const float* __restrict__ x,
                                              ushort* __restrict__ xf2,
                                              ushort* __restrict__ xf_t,
                                              float* __restrict__ rnorm,
                                              uint* __restrict__ mxbits,
                                              const float* __restrict__ g_w,
                                              const float* __restrict__ g_b,
                                              const float* __restrict__ w_w,
                                              const float* __restrict__ w_b,
                                              float* __restrict__ Mc) {
    if (blockIdx.x >= 512) {                           // ---- Mc blocks ----
        int idx = (blockIdx.x - 512) * 256 + threadIdx.x;
        if (idx < DD * DD) {
            int p = idx / DD, d = idx % DD;
            float acc = 0.f;
            #pragma unroll
            for (int o = 0; o < DD; ++o)
                acc = fmaf(w_w[p * DD + o], g_w[o * DD + d], acc);
            Mc[idx] = acc;
        } else if (idx < DD * DD + DD) {
            int p = idx - DD * DD;
            float acc = w_b[p];
            #pragma unroll
            for (int o = 0; o < DD; ++o)
                acc = fmaf(w_w[p * DD + o], g_b[o], acc);
            Mc[idx] = acc;
        }
        return;
    }
    __shared__ float ssp[8][33];
    int tid = threadIdx.x;
    int pix = tid & 31, j = tid >> 5;                  // d-group j: d = 8j..8j+7
    int n = blockIdx.x * 32 + pix;                     // blocks never cross b (128/batch)
    int b = n >> 12, nn = n & (NN - 1);
    int oh = nn >> 6, ow = nn & 63;
    const float* xb = x + (size_t)b * TC * HH * HH;
    ushort* x2 = xf2 + (size_t)b * DP * NN + nn;
    ushort row[8];
    float ss = 0.f;
    const int nh = (j < 7) ? 4 : 2;                    // j=7: only c1=14 (d 56..59)
    #pragma unroll
    for (int h = 0; h < 4; ++h) {
        if (h < nh) {
            int c1 = 2 * j + (h >> 1), r1 = h & 1;
            f2v v = *(const f2v*)&xb[(c1 * HH + oh * 2 + r1) * HH + ow * 2];
            ushort w0 = f2bf_bits(v[0]), w1 = f2bf_bits(v[1]);
            row[2 * h] = w0; row[2 * h + 1] = w1;
            float f0 = bf2f(w0), f1 = bf2f(w1);
            ss = fmaf(f0, f0, ss);
            ss = fmaf(f1, f1, ss);
            int d0 = 8 * j + 2 * h;
            x2[(size_t)d0 * NN] = w0;
            x2[(size_t)(d0 + 1) * NN] = w1;
        } else {
            row[2 * h] = 0; row[2 * h + 1] = 0;        // xf_t padding d 60..63 = 0
        }
    }
    if (j == 7) {                                      // xf2 special rows
        x2[(size_t)60 * NN] = (ushort)0x3F80;          // ones row -> l accumulator
        x2[(size_t)61 * NN] = 0;
        x2[(size_t)62 * NN] = 0;
        x2[(size_t)63 * NN] = 0;
    }
    *(s8v*)&xf_t[(size_t)n * DP + j * 8] = *(const s8v*)row;

    ssp[j][pix] = ss;
    __syncthreads();
    if (tid < 32) {
        float tot = ssp[0][tid] + ssp[1][tid] + ssp[2][tid] + ssp[3][tid]
                  + ssp[4][tid] + ssp[5][tid] + ssp[6][tid] + ssp[7][tid];
        float norm = sqrtf(tot) * 1.0002f;             // safety margin: m bounds row max
        rnorm[blockIdx.x * 32 + tid] = norm;
        float mv = norm;
        #pragma unroll
        for (int off = 1; off < 32; off <<= 1) mv = fmaxf(mv, __shfl_xor(mv, off));
        if (tid == 0) atomicMax(&mxbits[b], __float_as_uint(mv));
    }
}

// ---------- K3: flash attention, split-K=4, SWAPPED-OPERAND QK^T.
// S^T = mfma(K_frag, Q_frag): lane holds S[query=r][key=16*kt2+4g+reg]; nm scalar.
// MERGED phases: ONE P-phase (16 exp2 + 4 packed b64 writes), ONE PV-phase (8 MFMAs).
// Z = P.X^T with xf2 row 60 = 1 -> l. k_cout applies M and divides.
template <int NS>
__global__ __launch_bounds__(256, 2) void k_attn(const ushort* __restrict__ xf_t,
                                                 const ushort* __restrict__ x2_bf, // (B,64,N)
                                                 const float* __restrict__ rnorm,
                                                 const uint* __restrict__ mxbits,
                                                 ushort* __restrict__ O_bf) {  // (s,b,64,N) bf16
    __shared__ char K_lds[KT * 128];                   // 8 KB
    __shared__ char G_lds[DP * 128];                   // 8 KB (X^T tile)
    __shared__ char P_lds[NWAVE][16 * 128];            // 8 KB

    int p = blockIdx.x;
    int s, b, q0;
    if (NS == NSPLIT) {
        // XCD-aware: xcd = p&7; each XCD pair-half owns one batch (~1MB = L2-hot)
        int xcd = p & 7, slot = p >> 3;                // slot in [0,128)
        b = xcd >> 1;
        s = (xcd & 1) * 2 + (slot >> 6);               // NS=4: 2 splits per xcd-half
        q0 = (slot & 63) * QT;
    } else {
        s = 0;
        b = p >> 6;
        q0 = (p & 63) * QT;
    }
    int tid = threadIdx.x;
    int lane = tid & 63, wv = tid >> 6;
    int r = lane & 15, g = lane >> 4;

    const ushort* Xt = xf_t + (size_t)b * NN * DP;
    const ushort* Gb = x2_bf + (size_t)b * DP * NN;

    int qrow = q0 + wv * 16 + r;
    s8v qa[2];
    qa[0] = *(const s8v*)&Xt[(size_t)qrow * DP + g * 8];
    qa[1] = *(const s8v*)&Xt[(size_t)qrow * DP + 32 + g * 8];

    // fixed softmax shift: query is lane-fixed (= r) -> ONE scalar
    float mx = __uint_as_float(mxbits[b]);
    float nm = -rnorm[b * NN + qrow] * mx * L2E;

    f4v of[4];
    #pragma unroll
    for (int i = 0; i < 4; ++i) of[i] = (f4v){0.f, 0.f, 0.f, 0.f};

    // staging: 256 threads x two 16B units per buffer; row = e>>3, j = e&7
    const int e0 = tid, e1 = 256 + tid;
    const int kr0 = e0 >> 3, kj0 = e0 & 7;             // rows 0..31
    const int kr1 = e1 >> 3, kj1 = e1 & 7;             // rows 32..63
    const int kw0 = (kr0 * 128 + kj0 * 16) ^ ((kr0 & 7) << 4);
    const int kw1 = (kr1 * 128 + kj1 * 16) ^ ((kr1 & 7) << 4);
    s8v kp0, kp1, gp0, gp1;

    auto stage_regs = [&](int t) {
        int n0 = t * KT;
        kp0 = *(const s8v*)&Xt[(size_t)(n0 + kr0) * DP + kj0 * 8];
        kp1 = *(const s8v*)&Xt[(size_t)(n0 + kr1) * DP + kj1 * 8];
        gp0 = *(const s8v*)&Gb[(size_t)kr0 * NN + n0 + kj0 * 8];   // branch-free: 64 rows
        gp1 = *(const s8v*)&Gb[(size_t)kr1 * NN + n0 + kj1 * 8];
    };
    auto lds_write = [&]() {
        *(s8v*)(K_lds + kw0) = kp0;
        *(s8v*)(K_lds + kw1) = kp1;
        *(s8v*)(G_lds + kw0) = gp0;
        *(s8v*)(G_lds + kw1) = gp1;
    };

    const int t0 = s * (NTILES / NS);
    const int tend = t0 + NTILES / NS;
    char* Pw = P_lds[wv];

    stage_regs(t0);
    lds_write();
    __syncthreads();

    #pragma unroll 1
    for (int t = t0; t < tend; ++t) {
        bool more = (t + 1 < tend);
        if (more) stage_regs(t + 1);          // global loads in flight during compute

        // ---- S^T = K.Q^T (swapped operands; same LDS reads) ----
        f4v sf[4];
        #pragma unroll
        for (int i = 0; i < 4; ++i) sf[i] = (f4v){0.f, 0.f, 0.f, 0.f};
        #pragma unroll
        for (int kt2 = 0; kt2 < 4; ++kt2)
            #pragma unroll
            for (int kb = 0; kb < 2; ++kb) {
                int off = (((kt2 * 16 + r) * 128) + kb * 64 + g * 16) ^ ((r & 7) << 4);
                s8v bf = *(const s8v*)(K_lds + off);
                sf[kt2] = __builtin_amdgcn_mfma_f32_16x16x32_bf16(bf, qa[kb], sf[kt2], 0, 0, 0);
            }

        // ---- P (all 64 keys): 16 exp2 -> 4 packed b64 writes ----
        #pragma unroll
        for (int kt2 = 0; kt2 < 4; ++kt2) {
            uint p0 = __float_as_uint(__builtin_exp2f(fmaf(sf[kt2][0], L2E, nm)));
            uint p1 = __float_as_uint(__builtin_exp2f(fmaf(sf[kt2][1], L2E, nm)));
            uint p2 = __float_as_uint(__builtin_exp2f(fmaf(sf[kt2][2], L2E, nm)));
            uint p3 = __float_as_uint(__builtin_exp2f(fmaf(sf[kt2][3], L2E, nm)));
            uu2 dw = { (p0 >> 16) | (p1 & 0xFFFF0000u),
                       (p2 >> 16) | (p3 & 0xFFFF0000u) };
            int woff = ((r * 128) + 32 * kt2 + 8 * g) ^ ((r & 7) << 4);
            *(uu2*)(Pw + woff) = dw;
        }
        // ---- Z += P.X^T (both kb halves; wave-internal LDS is in-order) ----
        #pragma unroll
        for (int kb = 0; kb < 2; ++kb) {
            int poff = ((r * 128) + kb * 64 + g * 16) ^ ((r & 7) << 4);
            s8v pa = *(const s8v*)(Pw + poff);
            #pragma unroll
            for (int ot = 0; ot < 4; ++ot) {
                int goff = (((ot * 16 + r) * 128) + kb * 64 + g * 16) ^ ((r & 7) << 4);
                s8v gf = *(const s8v*)(G_lds + goff);
                of[ot] = __builtin_amdgcn_mfma_f32_16x16x32_bf16(pa, gf, of[ot], 0, 0, 0);
            }
        }

        if (more) {
            __syncthreads();                  // all waves done reading K/X^T
            lds_write();
            __syncthreads();                  // next tile staged
        }
    }

    // epilogue: unnormalized Z (+ l in col 60); k_cout applies M and divides
    int qb = q0 + wv * 16 + 4 * g;
    ushort* Ob = O_bf + ((size_t)(s * BB + b) * DP) * NN;
    #pragma unroll
    for (int ot = 0; ot < 4; ++ot) {
        int o = ot * 16 + r;
        u4v v = {f2bf_bits(of[ot][0]), f2bf_bits(of[ot][1]),
                 f2bf_bits(of[ot][2]), f2bf_bits(of[ot][3])};
        *(u4v*)&Ob[(size_t)o * NN + qb] = v;                 // coalesced 32B per r-group
    }
}

// ---------- K4 (fused combine+out): phase 1 u32 pixel-pair loads; phase 2
// o-pair f2v loads/stores. Block per 32 pixels, grid BB*128.
template <int NS>
__global__ __launch_bounds__(256) void k_cout(const ushort* __restrict__ O_bf,
                                              const float* __restrict__ Mc,
                                              const float* __restrict__ x,
                                              float* __restrict__ out) {
    __shared__ float ww[DD * DD];                      // 14.4 KB (= M)
    __shared__ float wb[DD];                           //          (= c)
    __shared__ float zlds[32][61];                     // 7.8 KB
    __shared__ float linv[32];

    int b  = blockIdx.x >> 7;                          // grid = BB*128
    int n0 = (blockIdx.x & 127) * 32;
    int tid = threadIdx.x;
    for (int i = tid; i < DD * DD; i += 256) ww[i] = Mc[i];
    if (tid < DD) wb[tid] = Mc[DD * DD + tid];

    // ---- phase 1 (vectorized): pixel pair pp = tid&15 (pixels 2pp, 2pp+1),
    //      o-group tid>>4 handles 4 o's; u32 loads = 2 pixels at once ----
    {
        int pp   = tid & 15;
        int ogrp = tid >> 4;                           // 0..15
        const ushort* Op = O_bf + (size_t)b * DP * NN + n0 + 2 * pp;
        #pragma unroll
        for (int i = 0; i < 4; ++i) {
            int o = ogrp * 4 + i;                      // 0..63
            if (o > DD) continue;                      // o<=60 processed
            float s0 = 0.f, s1 = 0.f;
            #pragma unroll
            for (int ss = 0; ss < NS; ++ss) {
                uint v = *(const uint*)&Op[(size_t)ss * BB * DP * NN + (size_t)o * NN];
                s0 += bf2f_lo(v);
                s1 += bf2f_hi(v);
            }
            if (o < DD) { zlds[2 * pp][o] = s0; zlds[2 * pp + 1][o] = s1; }
            else        { linv[2 * pp] = 1.0f / s0; linv[2 * pp + 1] = 1.0f / s1; }
        }
    }
    __syncthreads();

    // ---- phase 2: 4 o-pairs per thread (o = 2*(8k+ogrp)), f2v load/store ----
    int pix  = tid & 31;
    int ogrp = tid >> 5;                               // 0..7
    int n = n0 + pix;
    float li = linv[pix];
    int oh = n >> 6, ow = n & 63;
    #pragma unroll
    for (int k = 0; k < 4; ++k) {
        int o = 2 * (8 * k + ogrp);                    // even o: 0..62
        if (o < DD) {                                  // covers pairs (0,1)..(58,59)
            float a0 = 0.f, a1 = 0.f;
            #pragma unroll
            for (int d = 0; d < DD; ++d) {
                float z = zlds[pix][d];
                a0 = fmaf(ww[o * DD + d], z, a0);
                a1 = fmaf(ww[(o + 1) * DD + d], z, a1);
            }
            int c1 = o >> 2, r1 = (o >> 1) & 1;        // r2 = 0 then 1 (adjacent xi)
            size_t xi = ((size_t)(b * TC + c1) * HH + 2 * oh + r1) * HH + 2 * ow;
            f2v xv = *(const f2v*)&x[xi];
            f2v res = {fmaf(a0, li, wb[o]) + xv[0], fmaf(a1, li, wb[o + 1]) + xv[1]};
            *(f2v*)&out[xi] = res;
        }
    }
}

extern "C" void kernel_launch(void* const* d_in, const int* in_sizes, int n_in,
                              void* d_out, int out_size, void* d_ws, size_t ws_size,
                              hipStream_t stream) {
    const float* x   = (const float*)d_in[0];
    const float* g_w = (const float*)d_in[1];
    const float* g_b = (const float*)d_in[2];
    const float* w_w = (const float*)d_in[3];
    const float* w_b = (const float*)d_in[4];
    float* out = (float*)d_out;

    char* ws = (char*)d_ws;
    ushort* xf2    = (ushort*)ws;                      // 2,097,152 B (B,64,N)
    ushort* xf_t   = (ushort*)(ws + 2097152);          // 2,097,152 B (B,N,64)
    float*  rnorm  = (float*)(ws + 4194304);           // 65,536 B
    uint*   mxbits = (uint*)(ws + 4259840);            // 256 B
    float*  Mc     = (float*)(ws + 4260096);           // 16,384 B  (3600 M + 60 c)
    ushort* O_bf   = (ushort*)(ws + 4276480);          // 8,388,608 B (NS=4) -> end 12,665,088
    const size_t SPLIT_NEED = 12665088;

    hipMemsetAsync(mxbits, 0, BB * sizeof(uint), stream);
    k_prep<<<528, 256, 0, stream>>>(x, xf2, xf_t, rnorm, mxbits,
                                    g_w, g_b, w_w, w_b, Mc);   // blocks 512+ do Mc

    if (ws_size >= SPLIT_NEED) {
        k_attn<NSPLIT><<<NSPLIT * BB * (NN / QT), 256, 0, stream>>>(
            xf_t, xf2, rnorm, mxbits, O_bf);
        k_cout<NSPLIT><<<BB * 128, 256, 0, stream>>>(O_bf, Mc, x, out);
    } else {
        k_attn<1><<<BB * (NN / QT), 256, 0, stream>>>(
            xf_t, xf2, rnorm, mxbits, O_bf);
        k_cout<1><<<BB * 128, 256, 0, stream>>>(O_bf, Mc, x, out);
    }
}

// Round 34
// 56.634 us; speedup vs baseline: 1.5484x; 1.1447x over previous
//
#include <hip/hip_runtime.h>
#include <hip/hip_bf16.h>

// x: (B=4, T=5, C=3, H=128, W=128) fp32 ; R=2 ; D = 60 ; N = 4096
#define BB 4
#define TC 15
#define DD 60
#define NN 4096
#define HH 128
#define DP 64
#define KT 64
#define NWAVE 4
#define QT 64
#define NTILES 64
#define NSPLIT 4
#define L2E 1.4426950408889634f

typedef short s8v __attribute__((ext_vector_type(8)));   // 8 x bf16
typedef ushort u4v __attribute__((ext_vector_type(4)));
typedef uint  uu2 __attribute__((ext_vector_type(2)));
typedef float f4v __attribute__((ext_vector_type(4)));
typedef float f2v __attribute__((ext_vector_type(2)));

static __device__ __forceinline__ ushort f2bf_bits(float f) {
    __hip_bfloat16 h = __float2bfloat16(f);
    return *reinterpret_cast<ushort*>(&h);
}
static __device__ __forceinline__ float bf2f(ushort w) { return __uint_as_float((uint)w << 16); }
static __device__ __forceinline__ float bf2f_lo(uint u) { return __uint_as_float(u << 16); }
static __device__ __forceinline__ float bf2f_hi(uint u) { return __uint_as_float(u & 0xFFFF0000u); }

// ---------- K1 (fused): blocks 0..511 = d-parallel prep; blocks 512..527 = Mc.
// NO memset needed: per-block norm max written unconditionally to bmax[512]
// (attn reduces its batch's 128 entries itself). Mc: M = w_w.g_w ; c = w_w.g_b + w_b.
__global__ __launch_bounds__(256) void k_prep(const float* __restrict__ x,
                                              ushort* __restrict__ xf2,
                                              ushort* __restrict__ xf_t,
                                              float* __restrict__ rnorm,
                                              float* __restrict__ bmax,
                                              const float* __restrict__ g_w,
                                              const float* __restrict__ g_b,
                                              const float* __restrict__ w_w,
                                              const float* __restrict__ w_b,
                                              float* __restrict__ Mc) {
    if (blockIdx.x >= 512) {                           // ---- Mc blocks ----
        int idx = (blockIdx.x - 512) * 256 + threadIdx.x;
        if (idx < DD * DD) {
            int p = idx / DD, d = idx % DD;
            float acc = 0.f;
            #pragma unroll
            for (int o = 0; o < DD; ++o)
                acc = fmaf(w_w[p * DD + o], g_w[o * DD + d], acc);
            Mc[idx] = acc;
        } else if (idx < DD * DD + DD) {
            int p = idx - DD * DD;
            float acc = w_b[p];
            #pragma unroll
            for (int o = 0; o < DD; ++o)
                acc = fmaf(w_w[p * DD + o], g_b[o], acc);
            Mc[idx] = acc;
        }
        return;
    }
    __shared__ float ssp[8][33];
    int tid = threadIdx.x;
    int pix = tid & 31, j = tid >> 5;                  // d-group j: d = 8j..8j+7
    int n = blockIdx.x * 32 + pix;                     // blocks never cross b (128/batch)
    int b = n >> 12, nn = n & (NN - 1);
    int oh = nn >> 6, ow = nn & 63;
    const float* xb = x + (size_t)b * TC * HH * HH;
    ushort* x2 = xf2 + (size_t)b * DP * NN + nn;
    ushort row[8];
    float ss = 0.f;
    const int nh = (j < 7) ? 4 : 2;                    // j=7: only c1=14 (d 56..59)
    #pragma unroll
    for (int h = 0; h < 4; ++h) {
        if (h < nh) {
            int c1 = 2 * j + (h >> 1), r1 = h & 1;
            f2v v = *(const f2v*)&xb[(c1 * HH + oh * 2 + r1) * HH + ow * 2];
            ushort w0 = f2bf_bits(v[0]), w1 = f2bf_bits(v[1]);
            row[2 * h] = w0; row[2 * h + 1] = w1;
            float f0 = bf2f(w0), f1 = bf2f(w1);
            ss = fmaf(f0, f0, ss);
            ss = fmaf(f1, f1, ss);
            int d0 = 8 * j + 2 * h;
            x2[(size_t)d0 * NN] = w0;
            x2[(size_t)(d0 + 1) * NN] = w1;
        } else {
            row[2 * h] = 0; row[2 * h + 1] = 0;        // xf_t padding d 60..63 = 0
        }
    }
    if (j == 7) {                                      // xf2 special rows
        x2[(size_t)60 * NN] = (ushort)0x3F80;          // ones row -> l accumulator
        x2[(size_t)61 * NN] = 0;
        x2[(size_t)62 * NN] = 0;
        x2[(size_t)63 * NN] = 0;
    }
    *(s8v*)&xf_t[(size_t)n * DP + j * 8] = *(const s8v*)row;

    ssp[j][pix] = ss;
    __syncthreads();
    if (tid < 32) {
        float tot = ssp[0][tid] + ssp[1][tid] + ssp[2][tid] + ssp[3][tid]
                  + ssp[4][tid] + ssp[5][tid] + ssp[6][tid] + ssp[7][tid];
        float norm = sqrtf(tot) * 1.0002f;             // safety margin: m bounds row max
        rnorm[blockIdx.x * 32 + tid] = norm;
        float mv = norm;
        #pragma unroll
        for (int off = 1; off < 32; off <<= 1) mv = fmaxf(mv, __shfl_xor(mv, off));
        if (tid == 0) bmax[blockIdx.x] = mv;           // unconditional write: no init, no atomic
    }
}

// ---------- K3: flash attention, split-K=4, SWAPPED-OPERAND QK^T.
// S^T = mfma(K_frag, Q_frag): lane holds S[query=r][key=16*kt2+4g+reg]; nm scalar.
// Batch max reduced in-kernel from bmax[b*128..+127] (2 loads + 6-step shfl max).
// MERGED phases: ONE P-phase (16 exp2 + 4 packed b64 writes), ONE PV-phase (8 MFMAs).
// Z = P.X^T with xf2 row 60 = 1 -> l. k_cout applies M and divides.
template <int NS>
__global__ __launch_bounds__(256, 2) void k_attn(const ushort* __restrict__ xf_t,
                                                 const ushort* __restrict__ x2_bf, // (B,64,N)
                                                 const float* __restrict__ rnorm,
                                                 const float* __restrict__ bmax,
                                                 ushort* __restrict__ O_bf) {  // (s,b,64,N) bf16
    __shared__ char K_lds[KT * 128];                   // 8 KB
    __shared__ char G_lds[DP * 128];                   // 8 KB (X^T tile)
    __shared__ char P_lds[NWAVE][16 * 128];            // 8 KB

    int p = blockIdx.x;
    int s, b, q0;
    if (NS == NSPLIT) {
        // XCD-aware: xcd = p&7; each XCD pair-half owns one batch (~1MB = L2-hot)
        int xcd = p & 7, slot = p >> 3;                // slot in [0,128)
        b = xcd >> 1;
        s = (xcd & 1) * 2 + (slot >> 6);               // NS=4: 2 splits per xcd-half
        q0 = (slot & 63) * QT;
    } else {
        s = 0;
        b = p >> 6;
        q0 = (p & 63) * QT;
    }
    int tid = threadIdx.x;
    int lane = tid & 63, wv = tid >> 6;
    int r = lane & 15, g = lane >> 4;

    const ushort* Xt = xf_t + (size_t)b * NN * DP;
    const ushort* Gb = x2_bf + (size_t)b * DP * NN;

    int qrow = q0 + wv * 16 + r;
    s8v qa[2];
    qa[0] = *(const s8v*)&Xt[(size_t)qrow * DP + g * 8];
    qa[1] = *(const s8v*)&Xt[(size_t)qrow * DP + 32 + g * 8];

    // batch max from per-block maxima (128 entries, all lanes converge to max)
    float mx = fmaxf(bmax[b * 128 + lane], bmax[b * 128 + 64 + lane]);
    #pragma unroll
    for (int off = 1; off < 64; off <<= 1) mx = fmaxf(mx, __shfl_xor(mx, off));
    // fixed softmax shift: query is lane-fixed (= r) -> ONE scalar
    float nm = -rnorm[b * NN + qrow] * mx * L2E;

    f4v of[4];
    #pragma unroll
    for (int i = 0; i < 4; ++i) of[i] = (f4v){0.f, 0.f, 0.f, 0.f};

    // staging: 256 threads x two 16B units per buffer; row = e>>3, j = e&7
    const int e0 = tid, e1 = 256 + tid;
    const int kr0 = e0 >> 3, kj0 = e0 & 7;             // rows 0..31
    const int kr1 = e1 >> 3, kj1 = e1 & 7;             // rows 32..63
    const int kw0 = (kr0 * 128 + kj0 * 16) ^ ((kr0 & 7) << 4);
    const int kw1 = (kr1 * 128 + kj1 * 16) ^ ((kr1 & 7) << 4);
    s8v kp0, kp1, gp0, gp1;

    auto stage_regs = [&](int t) {
        int n0 = t * KT;
        kp0 = *(const s8v*)&Xt[(size_t)(n0 + kr0) * DP + kj0 * 8];
        kp1 = *(const s8v*)&Xt[(size_t)(n0 + kr1) * DP + kj1 * 8];
        gp0 = *(const s8v*)&Gb[(size_t)kr0 * NN + n0 + kj0 * 8];   // branch-free: 64 rows
        gp1 = *(const s8v*)&Gb[(size_t)kr1 * NN + n0 + kj1 * 8];
    };
    auto lds_write = [&]() {
        *(s8v*)(K_lds + kw0) = kp0;
        *(s8v*)(K_lds + kw1) = kp1;
        *(s8v*)(G_lds + kw0) = gp0;
        *(s8v*)(G_lds + kw1) = gp1;
    };

    const int t0 = s * (NTILES / NS);
    const int tend = t0 + NTILES / NS;
    char* Pw = P_lds[wv];

    stage_regs(t0);
    lds_write();
    __syncthreads();

    #pragma unroll 1
    for (int t = t0; t < tend; ++t) {
        bool more = (t + 1 < tend);
        if (more) stage_regs(t + 1);          // global loads in flight during compute

        // ---- S^T = K.Q^T (swapped operands; same LDS reads) ----
        f4v sf[4];
        #pragma unroll
        for (int i = 0; i < 4; ++i) sf[i] = (f4v){0.f, 0.f, 0.f, 0.f};
        #pragma unroll
        for (int kt2 = 0; kt2 < 4; ++kt2)
            #pragma unroll
            for (int kb = 0; kb < 2; ++kb) {
                int off = (((kt2 * 16 + r) * 128) + kb * 64 + g * 16) ^ ((r & 7) << 4);
                s8v bf = *(const s8v*)(K_lds + off);
                sf[kt2] = __builtin_amdgcn_mfma_f32_16x16x32_bf16(bf, qa[kb], sf[kt2], 0, 0, 0);
            }

        // ---- P (all 64 keys): 16 exp2 -> 4 packed b64 writes ----
        #pragma unroll
        for (int kt2 = 0; kt2 < 4; ++kt2) {
            uint p0 = __float_as_uint(__builtin_exp2f(fmaf(sf[kt2][0], L2E, nm)));
            uint p1 = __float_as_uint(__builtin_exp2f(fmaf(sf[kt2][1], L2E, nm)));
            uint p2 = __float_as_uint(__builtin_exp2f(fmaf(sf[kt2][2], L2E, nm)));
            uint p3 = __float_as_uint(__builtin_exp2f(fmaf(sf[kt2][3], L2E, nm)));
            uu2 dw = { (p0 >> 16) | (p1 & 0xFFFF0000u),
                       (p2 >> 16) | (p3 & 0xFFFF0000u) };
            int woff = ((r * 128) + 32 * kt2 + 8 * g) ^ ((r & 7) << 4);
            *(uu2*)(Pw + woff) = dw;
        }
        // ---- Z += P.X^T (both kb halves; wave-internal LDS is in-order) ----
        #pragma unroll
        for (int kb = 0; kb < 2; ++kb) {
            int poff = ((r * 128) + kb * 64 + g * 16) ^ ((r & 7) << 4);
            s8v pa = *(const s8v*)(Pw + poff);
            #pragma unroll
            for (int ot = 0; ot < 4; ++ot) {
                int goff = (((ot * 16 + r) * 128) + kb * 64 + g * 16) ^ ((r & 7) << 4);
                s8v gf = *(const s8v*)(G_lds + goff);
                of[ot] = __builtin_amdgcn_mfma_f32_16x16x32_bf16(pa, gf, of[ot], 0, 0, 0);
            }
        }

        if (more) {
            __syncthreads();                  // all waves done reading K/X^T
            lds_write();
            __syncthreads();                  // next tile staged
        }
    }

    // epilogue: unnormalized Z (+ l in col 60); k_cout applies M and divides
    int qb = q0 + wv * 16 + 4 * g;
    ushort* Ob = O_bf + ((size_t)(s * BB + b) * DP) * NN;
    #pragma unroll
    for (int ot = 0; ot < 4; ++ot) {
        int o = ot * 16 + r;
        u4v v = {f2bf_bits(of[ot][0]), f2bf_bits(of[ot][1]),
                 f2bf_bits(of[ot][2]), f2bf_bits(of[ot][3])};
        *(u4v*)&Ob[(size_t)o * NN + qb] = v;                 // coalesced 32B per r-group
    }
}

// ---------- K4 (fused combine+out): phase 1 u32 pixel-pair loads; phase 2
// o-pair f2v loads/stores. Block per 32 pixels, grid BB*128.
template <int NS>
__global__ __launch_bounds__(256) void k_cout(const ushort* __restrict__ O_bf,
                                              const float* __restrict__ Mc,
                                              const float* __restrict__ x,
                                              float* __restrict__ out) {
    __shared__ float ww[DD * DD];                      // 14.4 KB (= M)
    __shared__ float wb[DD];                           //          (= c)
    __shared__ float zlds[32][61];                     // 7.8 KB
    __shared__ float linv[32];

    int b  = blockIdx.x >> 7;                          // grid = BB*128
    int n0 = (blockIdx.x & 127) * 32;
    int tid = threadIdx.x;
    for (int i = tid; i < DD * DD; i += 256) ww[i] = Mc[i];
    if (tid < DD) wb[tid] = Mc[DD * DD + tid];

    // ---- phase 1 (vectorized): pixel pair pp = tid&15 (pixels 2pp, 2pp+1),
    //      o-group tid>>4 handles 4 o's; u32 loads = 2 pixels at once ----
    {
        int pp   = tid & 15;
        int ogrp = tid >> 4;                           // 0..15
        const ushort* Op = O_bf + (size_t)b * DP * NN + n0 + 2 * pp;
        #pragma unroll
        for (int i = 0; i < 4; ++i) {
            int o = ogrp * 4 + i;                      // 0..63
            if (o > DD) continue;                      // o<=60 processed
            float s0 = 0.f, s1 = 0.f;
            #pragma unroll
            for (int ss = 0; ss < NS; ++ss) {
                uint v = *(const uint*)&Op[(size_t)ss * BB * DP * NN + (size_t)o * NN];
                s0 += bf2f_lo(v);
                s1 += bf2f_hi(v);
            }
            if (o < DD) { zlds[2 * pp][o] = s0; zlds[2 * pp + 1][o] = s1; }
            else        { linv[2 * pp] = 1.0f / s0; linv[2 * pp + 1] = 1.0f / s1; }
        }
    }
    __syncthreads();

    // ---- phase 2: 4 o-pairs per thread (o = 2*(8k+ogrp)), f2v load/store ----
    int pix  = tid & 31;
    int ogrp = tid >> 5;                               // 0..7
    int n = n0 + pix;
    float li = linv[pix];
    int oh = n >> 6, ow = n & 63;
    #pragma unroll
    for (int k = 0; k < 4; ++k) {
        int o = 2 * (8 * k + ogrp);                    // even o: 0..62
        if (o < DD) {                                  // covers pairs (0,1)..(58,59)
            float a0 = 0.f, a1 = 0.f;
            #pragma unroll
            for (int d = 0; d < DD; ++d) {
                float z = zlds[pix][d];
                a0 = fmaf(ww[o * DD + d], z, a0);
                a1 = fmaf(ww[(o + 1) * DD + d], z, a1);
            }
            int c1 = o >> 2, r1 = (o >> 1) & 1;        // r2 = 0 then 1 (adjacent xi)
            size_t xi = ((size_t)(b * TC + c1) * HH + 2 * oh + r1) * HH + 2 * ow;
            f2v xv = *(const f2v*)&x[xi];
            f2v res = {fmaf(a0, li, wb[o]) + xv[0], fmaf(a1, li, wb[o + 1]) + xv[1]};
            *(f2v*)&out[xi] = res;
        }
    }
}

extern "C" void kernel_launch(void* const* d_in, const int* in_sizes, int n_in,
                              void* d_out, int out_size, void* d_ws, size_t ws_size,
                              hipStream_t stream) {
    const float* x   = (const float*)d_in[0];
    const float* g_w = (const float*)d_in[1];
    const float* g_b = (const float*)d_in[2];
    const float* w_w = (const float*)d_in[3];
    const float* w_b = (const float*)d_in[4];
    float* out = (float*)d_out;

    char* ws = (char*)d_ws;
    ushort* xf2    = (ushort*)ws;                      // 2,097,152 B (B,64,N)
    ushort* xf_t   = (ushort*)(ws + 2097152);          // 2,097,152 B (B,N,64)
    float*  rnorm  = (float*)(ws + 4194304);           // 65,536 B
    float*  bmax   = (float*)(ws + 4259840);           // 2,048 B (512 per-block maxima)
    float*  Mc     = (float*)(ws + 4261888);           // 16,384 B  (3600 M + 60 c)
    ushort* O_bf   = (ushort*)(ws + 4278272);          // 8,388,608 B (NS=4) -> end 12,666,880
    const size_t SPLIT_NEED = 12666880;

    k_prep<<<528, 256, 0, stream>>>(x, xf2, xf_t, rnorm, bmax,
                                    g_w, g_b, w_w, w_b, Mc);   // blocks 512+ do Mc

    if (ws_size >= SPLIT_NEED) {
        k_attn<NSPLIT><<<NSPLIT * BB * (NN / QT), 256, 0, stream>>>(
            xf_t, xf2, rnorm, bmax, O_bf);
        k_cout<NSPLIT><<<BB * 128, 256, 0, stream>>>(O_bf, Mc, x, out);
    } else {
        k_attn<1><<<BB * (NN / QT), 256, 0, stream>>>(
            xf_t, xf2, rnorm, bmax, O_bf);
        k_cout<1><<<BB * 128, 256, 0, stream>>>(O_bf, Mc, x, out);
    }
}